// Round 6
// baseline (941.328 us; speedup 1.0000x reference)
//
#include <hip/hip_runtime.h>
#include <math.h>

#define TT 512
#define BB 32
#define SS 64
#define AA 8
#define DD 32
#define EPSF 1e-6f
#define SEPS (64.0f * 1e-6f)   // reference adds EPS under the 64-term i-sum
#define TS 68                  // (fallback kernel) tile row stride

__device__ __forceinline__ int   f2i(float x){ return __float_as_int(x); }
__device__ __forceinline__ float i2f(int x){ return __int_as_float(x); }
__device__ __forceinline__ float readlane_f(float v, int l){
  return i2f(__builtin_amdgcn_readlane(f2i(v), l));
}
template<int CTRL, int RMASK>
__device__ __forceinline__ float dpp_add(float x){
  return x + i2f(__builtin_amdgcn_update_dpp(0, f2i(x), CTRL, RMASK, 0xf, true));
}
// 64-lane sum, pure VALU (DPP), result broadcast via readlane 63
__device__ __forceinline__ float wave_sum_dpp(float x){
  x = dpp_add<0x111, 0xf>(x);
  x = dpp_add<0x112, 0xf>(x);
  x = dpp_add<0x114, 0xf>(x);
  x = dpp_add<0x118, 0xf>(x);
  x = dpp_add<0x142, 0xa>(x);
  x = dpp_add<0x143, 0xc>(x);
  return readlane_f(x, 63);
}
__device__ __forceinline__ float wave_sum(float v){
  #pragma unroll
  for (int m = 1; m < 64; m <<= 1) v += __shfl_xor(v, m, 64);
  return v;
}
__device__ __forceinline__ float wave_max(float v){
  #pragma unroll
  for (int m = 1; m < 64; m <<= 1) v = fmaxf(v, __shfl_xor(v, m, 64));
  return v;
}
#define BARRIER() asm volatile("s_waitcnt lgkmcnt(0)\n\ts_barrier" ::: "memory")

// --- kernel 0: invvar = exp(-logv), cs[s] = sum_d logv + D*log(2pi)
__global__ void prep_kernel(const float* __restrict__ logv,
                            float* __restrict__ iv, float* __restrict__ cs){
  int gid = blockIdx.x * blockDim.x + threadIdx.x;
  if (gid < SS * DD) iv[gid] = __expf(-logv[gid]);
  if (gid < SS){
    float s = 0.f;
    #pragma unroll
    for (int d = 0; d < DD; ++d) s += logv[gid * DD + d];
    cs[gid] = s + (float)DD * 1.8378770664093453f;
  }
}

// --- kernel 1: slx[t,b,s] = lx - rowmax(lx)
__global__ __launch_bounds__(256) void logpx_kernel(
    const float* __restrict__ x, const float* __restrict__ mu,
    const float* __restrict__ iv, const float* __restrict__ cs,
    float* __restrict__ slx_out){
  const int lane = threadIdx.x & 63;
  const int w = threadIdx.x >> 6;
  const int row = blockIdx.x * 4 + w;
  const float* __restrict__ xp  = x  + row * DD;
  const float* __restrict__ mup = mu + lane * DD;
  const float* __restrict__ ivp = iv + lane * DD;
  float acc = 0.f;
  #pragma unroll
  for (int d = 0; d < DD; ++d){
    float diff = xp[d] - mup[d];
    acc = fmaf(diff * diff, ivp[d], acc);
  }
  float lx = -0.5f * (acc + cs[lane]);
  float mx = wave_max(lx);
  slx_out[row * SS + lane] = lx - mx;
}

// --- produce: normalized transition tiles for a fwd window (transposed P^T[j][i])
// and a bwd window (P[i][j]). Fully parallel across all CUs.
// grid: f_cnt*8 + b_cnt*8 blocks (4 b's per block), 256 threads (lane=i, wave=col chunk).
__global__ __launch_bounds__(256) void produce_kernel(
    const float* __restrict__ a, const float* __restrict__ w_base,
    const float* __restrict__ w_act, float* __restrict__ ET,
    float* __restrict__ E, int f_lo, int f_cnt, int b_lo, int b_cnt){
  const int lane = threadIdx.x & 63;
  const int wv = threadIdx.x >> 6;
  const int jb = wv * 16;
  int blk = blockIdx.x;
  const bool isF = blk < f_cnt * 8;
  if (!isF) blk -= f_cnt * 8;
  const int rel = blk >> 3;
  const int b0 = (blk & 7) * 4;
  const int t = (isF ? f_lo : b_lo) + rel;

  // weight slice: rows i=lane, cols jb..jb+15
  float4 wb4[4], wa4[8][4];
  {
    const float4* wbp = (const float4*)(w_base + lane * SS + jb);
    #pragma unroll
    for (int q = 0; q < 4; ++q) wb4[q] = wbp[q];
    #pragma unroll
    for (int k = 0; k < 8; ++k){
      const float4* wap = (const float4*)(w_act + ((k * SS + lane) * SS) + jb);
      #pragma unroll
      for (int q = 0; q < 4; ++q) wa4[k][q] = wap[q];
    }
  }
  __shared__ float part[4][4][SS];
  #pragma unroll
  for (int g = 0; g < 4; ++g){
    const int b = b0 + g;
    float aa[8];
    const float* __restrict__ ap = a + (t * BB + b) * AA;
    #pragma unroll
    for (int k = 0; k < 8; ++k) aa[k] = ap[k];
    float4 uv[4];
    #pragma unroll
    for (int q = 0; q < 4; ++q){
      uv[q] = wb4[q];
      #pragma unroll
      for (int k = 0; k < 8; ++k){
        uv[q].x = fmaf(aa[k], wa4[k][q].x, uv[q].x);
        uv[q].y = fmaf(aa[k], wa4[k][q].y, uv[q].y);
        uv[q].z = fmaf(aa[k], wa4[k][q].z, uv[q].z);
        uv[q].w = fmaf(aa[k], wa4[k][q].w, uv[q].w);
      }
    }
    float ev[16]; float rpart = 0.f;
    #pragma unroll
    for (int q = 0; q < 4; ++q){
      ev[4*q+0] = __expf(uv[q].x); ev[4*q+1] = __expf(uv[q].y);
      ev[4*q+2] = __expf(uv[q].z); ev[4*q+3] = __expf(uv[q].w);
      rpart += ev[4*q+0] + ev[4*q+1] + ev[4*q+2] + ev[4*q+3];
    }
    part[g][wv][lane] = rpart;
    __syncthreads();
    float rs = part[g][0][lane] + part[g][1][lane]
             + part[g][2][lane] + part[g][3][lane];
    float rn = __builtin_amdgcn_rcpf(rs);
    const size_t tb = (size_t)(rel * BB + b) << 12;   // 4096 floats per tile
    if (isF){
      float* __restrict__ dst = ET + tb;              // P^T[j][i]
      #pragma unroll
      for (int c = 0; c < 16; ++c) dst[(jb + c) * SS + lane] = ev[c] * rn;
    } else {
      float* __restrict__ dst = E + tb;               // P[i][j]
      #pragma unroll
      for (int q = 0; q < 4; ++q){
        *(float4*)&dst[lane * SS + jb + 4*q] =
          make_float4(ev[4*q]*rn, ev[4*q+1]*rn, ev[4*q+2]*rn, ev[4*q+3]*rn);
      }
    }
  }
}

// --- scan over one window: 64 blocks x 64 threads (1 wave per chain, no LDS,
// no barriers). blocks 0..31 fwd chains, 32..63 bwd chains.
__global__ __launch_bounds__(64, 1) void scan_win_kernel(
    const float* __restrict__ slx, const float* __restrict__ mask,
    const float* __restrict__ il,
    const float* __restrict__ ET, const float* __restrict__ E,
    float* __restrict__ alpha, float* __restrict__ log_beta,
    float* __restrict__ fwd_u, float* __restrict__ bwd_b,
    int f_lo, int f_cnt, int b_lo, int b_cnt){
  const int lane = threadIdx.x;
  if (blockIdx.x < BB){
    // ---------------- FORWARD ----------------
    const int b = blockIdx.x;
    float u, c;
    if (f_lo == 0){
      u = __expf(slx[b * SS + lane] + il[lane]);
      c = __builtin_amdgcn_rcpf(wave_sum_dpp(u));
      alpha[b * SS + lane] = u * c;
    } else {
      u = fwd_u[b * SS + lane];
      c = __builtin_amdgcn_rcpf(wave_sum_dpp(u));
    }
    float4 eA[16], eB[16]; float slA, slB;
    int r = 0;
    {
      const float4* rp = (const float4*)ET + ((size_t)(0 * BB + b) << 10) + lane * 16;
      #pragma unroll
      for (int q = 0; q < 16; ++q) eA[q] = rp[q];
      slA = slx[(f_lo + 1) * (BB * SS) + b * SS + lane];
    }
    auto fstep = [&](float4 (&cur)[16], float4 (&nxt)[16], float& slc, float& sln){
      const int rn = (r + 1 < f_cnt) ? r + 1 : r;
      const float4* np = (const float4*)ET + ((size_t)(rn * BB + b) << 10) + lane * 16;
      #pragma unroll
      for (int q = 0; q < 16; ++q) nxt[q] = np[q];
      int tn = f_lo + 2 + r; if (tn > TT - 1) tn = TT - 1;
      sln = slx[tn * (BB * SS) + b * SS + lane];
      float a0 = 0.f, a1 = 0.f, a2 = 0.f, a3 = 0.f;
      #pragma unroll
      for (int q = 0; q < 16; ++q){
        a0 = fmaf(readlane_f(u, 4*q + 0), cur[q].x, a0);
        a1 = fmaf(readlane_f(u, 4*q + 1), cur[q].y, a1);
        a2 = fmaf(readlane_f(u, 4*q + 2), cur[q].z, a2);
        a3 = fmaf(readlane_f(u, 4*q + 3), cur[q].w, a3);
      }
      float S = (a0 + a1) + (a2 + a3);
      u = __expf(slc) * fmaf(c, S, SEPS);
      c = __builtin_amdgcn_rcpf(wave_sum_dpp(u));
      alpha[(f_lo + 1 + r) * (BB * SS) + b * SS + lane] = u * c;
      ++r;
    };
    for (;;){
      fstep(eA, eB, slA, slB); if (r >= f_cnt) break;
      fstep(eB, eA, slB, slA); if (r >= f_cnt) break;
    }
    fwd_u[b * SS + lane] = u;
  } else {
    // ---------------- BACKWARD ----------------
    const int bb = blockIdx.x - BB;
    float breg;
    if (b_lo + b_cnt == TT - 1){
      breg = 0.f;
      log_beta[(TT - 1) * (BB * SS) + bb * SS + lane] = 0.f;
    } else {
      breg = bwd_b[bb * SS + lane];
    }
    float4 eA[16], eB[16]; float slA, slB, mA, mB;
    int r = b_cnt - 1;
    {
      const float4* rp = (const float4*)E + ((size_t)(r * BB + bb) << 10) + lane * 16;
      #pragma unroll
      for (int q = 0; q < 16; ++q) eA[q] = rp[q];
      slA = slx[(b_lo + r + 1) * (BB * SS) + bb * SS + lane];
      mA  = mask[(b_lo + r + 1) * BB + bb];
    }
    auto bstep = [&](float4 (&cur)[16], float4 (&nxt)[16],
                     float& slc, float& sln, float& mc, float& mn){
      const int rn = (r - 1 >= 0) ? r - 1 : 0;
      const float4* np = (const float4*)E + ((size_t)(rn * BB + bb) << 10) + lane * 16;
      #pragma unroll
      for (int q = 0; q < 16; ++q) nxt[q] = np[q];
      sln = slx[(b_lo + rn + 1) * (BB * SS) + bb * SS + lane];
      mn  = mask[(b_lo + rn + 1) * BB + bb];
      float wgt = __expf(slc + breg);
      float W = wave_sum_dpp(wgt);            // overlaps matvec (pure VALU)
      float rW = __builtin_amdgcn_rcpf(W);
      float a0 = 0.f, a1 = 0.f, a2 = 0.f, a3 = 0.f;
      #pragma unroll
      for (int q = 0; q < 16; ++q){
        a0 = fmaf(readlane_f(wgt, 4*q + 0), cur[q].x, a0);
        a1 = fmaf(readlane_f(wgt, 4*q + 1), cur[q].y, a1);
        a2 = fmaf(readlane_f(wgt, 4*q + 2), cur[q].z, a2);
        a3 = fmaf(readlane_f(wgt, 4*q + 3), cur[q].w, a3);
      }
      // v = log( sum_j (p_ij+EPS) wgt_j / W )  (shift-relative LSE)
      float v = __logf(fmaf((a0 + a1) + (a2 + a3), rW, EPSF));
      breg = (mc == 1.0f) ? v : 0.0f;
      log_beta[(b_lo + r) * (BB * SS) + bb * SS + lane] = breg;
      --r;
    };
    for (;;){
      bstep(eA, eB, slA, slB, mA, mB); if (r < 0) break;
      bstep(eB, eA, slB, slA, mB, mA); if (r < 0) break;
    }
    bwd_b[bb * SS + lane] = breg;
  }
}

// ================== R5 fallback scan (proven, 12.6 MB ws) ==================
__global__ __launch_bounds__(768) void scan_kernel(
    const float* __restrict__ slx, const float* __restrict__ mask,
    const float* __restrict__ il, const float* __restrict__ a,
    const float* __restrict__ w_base, const float* __restrict__ w_act,
    float* __restrict__ alpha, float* __restrict__ log_beta){
  const int lane = threadIdx.x & 63;
  const int w    = threadIdx.x >> 6;
  const bool is_fwd = (blockIdx.x < BB);
  const int b = is_fwd ? blockIdx.x : (blockIdx.x - BB);
  __shared__ __align__(16) float tile[3][SS * TS];
  __shared__ float rsp[3][8][SS];
  __shared__ float fpart[2][4][SS];
  __shared__ __align__(16) float aLDS[TT * AA];
  __shared__ float mLDS[TT];
  for (int idx = threadIdx.x; idx < TT * AA; idx += 768){
    int t = idx >> 3, k = idx & 7;
    aLDS[idx] = a[(t * BB + b) * AA + k];
  }
  for (int idx = threadIdx.x; idx < TT; idx += 768)
    mLDS[idx] = mask[idx * BB + b];
  if (w >= 4){
    const int pw = w - 4;
    const int jb = pw * 8;
    float wb[8], wa[8][8];
    #pragma unroll
    for (int jj = 0; jj < 8; ++jj){
      wb[jj] = w_base[lane * SS + jb + jj];
      #pragma unroll
      for (int k = 0; k < 8; ++k)
        wa[k][jj] = w_act[(k * SS + lane) * SS + jb + jj];
    }
    float aa[8], aan[8];
    {
      const int t0 = is_fwd ? 0 : (TT - 2);
      const float* __restrict__ ap = a + (t0 * BB + b) * AA;
      #pragma unroll
      for (int k = 0; k < 8; ++k) aa[k] = ap[k];
      const int t1 = is_fwd ? 1 : (TT - 3);
      const float* __restrict__ ap1 = a + (t1 * BB + b) * AA;
      #pragma unroll
      for (int k = 0; k < 8; ++k) aan[k] = ap1[k];
    }
    {
      float ev[8]; float racc = 0.f;
      #pragma unroll
      for (int jj = 0; jj < 8; ++jj){
        float u = wb[jj];
        #pragma unroll
        for (int k = 0; k < 8; ++k) u = fmaf(aa[k], wa[k][jj], u);
        ev[jj] = __expf(u); racc += ev[jj];
      }
      *(float4*)&tile[0][lane * TS + jb]     = make_float4(ev[0],ev[1],ev[2],ev[3]);
      *(float4*)&tile[0][lane * TS + jb + 4] = make_float4(ev[4],ev[5],ev[6],ev[7]);
      rsp[0][pw][lane] = racc;
    }
    BARRIER();
    int tw = 1;
    for (int s = 0; s < TT - 1; ++s){
      if (s <= TT - 3){
        #pragma unroll
        for (int k = 0; k < 8; ++k) aa[k] = aan[k];
        if (s + 1 <= TT - 3){
          const int tn = is_fwd ? (s + 2) : (TT - 4 - s);
          #pragma unroll
          for (int k = 0; k < 8; ++k) aan[k] = aLDS[tn * AA + k];
        }
        float ev[8]; float racc = 0.f;
        #pragma unroll
        for (int jj = 0; jj < 8; ++jj){
          float u = wb[jj];
          #pragma unroll
          for (int k = 0; k < 8; ++k) u = fmaf(aa[k], wa[k][jj], u);
          ev[jj] = __expf(u); racc += ev[jj];
        }
        *(float4*)&tile[tw][lane * TS + jb]     = make_float4(ev[0],ev[1],ev[2],ev[3]);
        *(float4*)&tile[tw][lane * TS + jb + 4] = make_float4(ev[4],ev[5],ev[6],ev[7]);
        rsp[tw][pw][lane] = racc;
        tw = (tw == 2) ? 0 : tw + 1;
      }
      BARRIER();
    }
  } else if (is_fwd){
    const int wb16 = __builtin_amdgcn_readfirstlane(w * 16);
    float u = __expf(slx[b * SS + lane] + il[lane]);
    float c = __builtin_amdgcn_rcpf(wave_sum_dpp(u));
    if (w == 0) alpha[b * SS + lane] = u * c;
    float slxn = slx[(BB + b) * SS + lane];
    float elxc = 0.f;
    BARRIER();
    int ts = 0;
    for (int s = 0; s < TT - 1; ++s){
      if (s > 0){
        const int fs = (s - 1) & 1;
        float S = (fpart[fs][0][lane] + fpart[fs][1][lane])
                + (fpart[fs][2][lane] + fpart[fs][3][lane]);
        u = elxc * fmaf(c, S, SEPS);
        c = __builtin_amdgcn_rcpf(wave_sum_dpp(u));
        if (w == 0) alpha[(s * BB + b) * SS + lane] = u * c;
      }
      float rs = ((rsp[ts][0][lane] + rsp[ts][1][lane]) + (rsp[ts][2][lane] + rsp[ts][3][lane]))
               + ((rsp[ts][4][lane] + rsp[ts][5][lane]) + (rsp[ts][6][lane] + rsp[ts][7][lane]));
      float va = u * __builtin_amdgcn_rcpf(rs);
      const float* __restrict__ tp = &tile[ts][0];
      float a0 = 0.f, a1 = 0.f, a2 = 0.f, a3 = 0.f;
      #pragma unroll
      for (int r = 0; r < 16; r += 4){
        a0 = fmaf(readlane_f(va, wb16 + r    ), tp[(wb16 + r    ) * TS + lane], a0);
        a1 = fmaf(readlane_f(va, wb16 + r + 1), tp[(wb16 + r + 1) * TS + lane], a1);
        a2 = fmaf(readlane_f(va, wb16 + r + 2), tp[(wb16 + r + 2) * TS + lane], a2);
        a3 = fmaf(readlane_f(va, wb16 + r + 3), tp[(wb16 + r + 3) * TS + lane], a3);
      }
      fpart[s & 1][w][lane] = (a0 + a1) + (a2 + a3);
      elxc = __expf(slxn);
      if (s + 2 <= TT - 1) slxn = slx[((s + 2) * BB + b) * SS + lane];
      ts = (ts == 2) ? 0 : ts + 1;
      BARRIER();
    }
    {
      const int fs = (TT - 2) & 1;
      float S = (fpart[fs][0][lane] + fpart[fs][1][lane])
              + (fpart[fs][2][lane] + fpart[fs][3][lane]);
      u = elxc * fmaf(c, S, SEPS);
      c = __builtin_amdgcn_rcpf(wave_sum_dpp(u));
      if (w == 0) alpha[((TT - 1) * BB + b) * SS + lane] = u * c;
    }
  } else {
    const int wb16 = __builtin_amdgcn_readfirstlane(w * 16);
    float breg = 0.f, rWc = 1.f;
    if (w == 0) log_beta[((TT - 1) * BB + b) * SS + lane] = 0.f;
    float slxc = slx[((TT - 1) * BB + b) * SS + lane];
    float mprev = 1.f;
    BARRIER();
    int ts = 0, pts = 2;
    for (int s = 0; s < TT - 1; ++s){
      if (s > 0){
        const int fs = (s - 1) & 1;
        float eh = (fpart[fs][0][lane] + fpart[fs][1][lane])
                 + (fpart[fs][2][lane] + fpart[fs][3][lane]);
        float rsv = ((rsp[pts][0][lane] + rsp[pts][1][lane]) + (rsp[pts][2][lane] + rsp[pts][3][lane]))
                  + ((rsp[pts][4][lane] + rsp[pts][5][lane]) + (rsp[pts][6][lane] + rsp[pts][7][lane]));
        float v = __logf(fmaf(eh * __builtin_amdgcn_rcpf(rsv), rWc, EPSF));
        breg = (mprev == 1.0f) ? v : 0.0f;
        if (w == 0) log_beta[((TT - 1 - s) * BB + b) * SS + lane] = breg;
      }
      float wgt = __expf(slxc + breg);
      float W = wave_sum_dpp(wgt);
      rWc = __builtin_amdgcn_rcpf(W);
      const float* __restrict__ tp = &tile[ts][lane * TS + wb16];
      float4 e0 = *(const float4*)(tp);
      float4 e1 = *(const float4*)(tp + 4);
      float4 e2 = *(const float4*)(tp + 8);
      float4 e3 = *(const float4*)(tp + 12);
      float a0 = 0.f, a1 = 0.f, a2 = 0.f, a3 = 0.f;
      a0 = fmaf(readlane_f(wgt, wb16 + 0),  e0.x, a0);
      a1 = fmaf(readlane_f(wgt, wb16 + 1),  e0.y, a1);
      a2 = fmaf(readlane_f(wgt, wb16 + 2),  e0.z, a2);
      a3 = fmaf(readlane_f(wgt, wb16 + 3),  e0.w, a3);
      a0 = fmaf(readlane_f(wgt, wb16 + 4),  e1.x, a0);
      a1 = fmaf(readlane_f(wgt, wb16 + 5),  e1.y, a1);
      a2 = fmaf(readlane_f(wgt, wb16 + 6),  e1.z, a2);
      a3 = fmaf(readlane_f(wgt, wb16 + 7),  e1.w, a3);
      a0 = fmaf(readlane_f(wgt, wb16 + 8),  e2.x, a0);
      a1 = fmaf(readlane_f(wgt, wb16 + 9),  e2.y, a1);
      a2 = fmaf(readlane_f(wgt, wb16 + 10), e2.z, a2);
      a3 = fmaf(readlane_f(wgt, wb16 + 11), e2.w, a3);
      a0 = fmaf(readlane_f(wgt, wb16 + 12), e3.x, a0);
      a1 = fmaf(readlane_f(wgt, wb16 + 13), e3.y, a1);
      a2 = fmaf(readlane_f(wgt, wb16 + 14), e3.z, a2);
      a3 = fmaf(readlane_f(wgt, wb16 + 15), e3.w, a3);
      fpart[s & 1][w][lane] = (a0 + a1) + (a2 + a3);
      mprev = mLDS[TT - 1 - s];
      if (s <= TT - 3) slxc = slx[((TT - 2 - s) * BB + b) * SS + lane];
      pts = ts; ts = (ts == 2) ? 0 : ts + 1;
      BARRIER();
    }
    {
      const int fs = (TT - 2) & 1;
      float eh = (fpart[fs][0][lane] + fpart[fs][1][lane])
               + (fpart[fs][2][lane] + fpart[fs][3][lane]);
      float rsv = ((rsp[pts][0][lane] + rsp[pts][1][lane]) + (rsp[pts][2][lane] + rsp[pts][3][lane]))
                + ((rsp[pts][4][lane] + rsp[pts][5][lane]) + (rsp[pts][6][lane] + rsp[pts][7][lane]));
      float v = __logf(fmaf(eh * __builtin_amdgcn_rcpf(rsv), rWc, EPSF));
      breg = (mprev == 1.0f) ? v : 0.0f;
      if (w == 0) log_beta[b * SS + lane] = breg;
    }
  }
}

// --- q_z = softmax(log(alpha+EPS) + log_beta)
__global__ __launch_bounds__(256) void qz_kernel(
    const float* __restrict__ alpha, const float* __restrict__ log_beta,
    float* __restrict__ out){
  const int lane = threadIdx.x & 63;
  const int w = threadIdx.x >> 6;
  const int row = blockIdx.x * 4 + w;
  float v = __logf(alpha[row * SS + lane] + EPSF) + log_beta[row * SS + lane];
  float mx = wave_max(v);
  float e = __expf(v - mx);
  float sm = wave_sum(e);
  out[row * SS + lane] = e * __builtin_amdgcn_rcpf(sm);
}

extern "C" void kernel_launch(void* const* d_in, const int* in_sizes, int n_in,
                              void* d_out, int out_size, void* d_ws, size_t ws_size,
                              hipStream_t stream){
  const float* x      = (const float*)d_in[0];
  const float* a      = (const float*)d_in[1];
  const float* mask   = (const float*)d_in[2];
  const float* mu     = (const float*)d_in[3];
  const float* logv   = (const float*)d_in[4];
  const float* il     = (const float*)d_in[5];
  const float* w_base = (const float*)d_in[6];
  const float* w_act  = (const float*)d_in[7];
  float* out = (float*)d_out;

  float* ws = (float*)d_ws;
  const size_t TBS = (size_t)TT * BB * SS;
  float* iv       = ws;                   // 2048 (+cs, pad to 4096)
  float* cs       = ws + 2048;
  float* slx      = ws + 4096;
  float* alpha    = slx + TBS;
  float* log_beta = alpha + TBS;
  float* fwd_u    = log_beta + TBS;       // 2048
  float* bwd_b    = fwd_u + 2048;         // 2048 (pad to 8192)
  const size_t base = 4096 + 3 * TBS + 8192;
  float* ET = ws + base;

  // choose largest window W whose two E-buffers fit in ws
  const size_t avail = (ws_size / 4 > base) ? (ws_size / 4 - base) : 0;
  int W = 0;
  const int tiers[5] = {128, 64, 32, 16, 8};
  for (int i = 0; i < 5; ++i){
    if ((size_t)tiers[i] * 2 * BB * 4096 <= avail){ W = tiers[i]; break; }
  }

  prep_kernel<<<8, 256, 0, stream>>>(logv, iv, cs);
  logpx_kernel<<<TT * BB / 4, 256, 0, stream>>>(x, mu, iv, cs, slx);
  if (W > 0){
    float* E = ET + (size_t)W * BB * 4096;
    const int nw = (TT - 1 + W - 1) / W;
    for (int k = 0; k < nw; ++k){
      const int f_lo = k * W;
      const int f_cnt = ((TT - 1) - f_lo < W) ? ((TT - 1) - f_lo) : W;
      const int b_hi = (TT - 1) - k * W;
      const int b_lo = (b_hi - W > 0) ? (b_hi - W) : 0;
      const int b_cnt = b_hi - b_lo;
      produce_kernel<<<f_cnt * 8 + b_cnt * 8, 256, 0, stream>>>(
          a, w_base, w_act, ET, E, f_lo, f_cnt, b_lo, b_cnt);
      scan_win_kernel<<<2 * BB, 64, 0, stream>>>(
          slx, mask, il, ET, E, alpha, log_beta, fwd_u, bwd_b,
          f_lo, f_cnt, b_lo, b_cnt);
    }
  } else {
    scan_kernel<<<2 * BB, 768, 0, stream>>>(slx, mask, il, a, w_base, w_act,
                                            alpha, log_beta);
  }
  qz_kernel<<<TT * BB / 4, 256, 0, stream>>>(alpha, log_beta, out);
}

// Round 7
// 731.239 us; speedup vs baseline: 1.2873x; 1.2873x over previous
//
#include <hip/hip_runtime.h>
#include <math.h>

#define TT 512
#define BB 32
#define SS 64
#define AA 8
#define DD 32
#define EPSF 1e-6f
#define SEPS (64.0f * 1e-6f)   // reference adds EPS under the 64-term i-sum
#define TS 68                  // (fallback kernel) tile row stride

typedef _Float16 f16;
typedef f16 h8 __attribute__((ext_vector_type(8)));   // 16 B = 8 halves

__device__ __forceinline__ int   f2i(float x){ return __float_as_int(x); }
__device__ __forceinline__ float i2f(int x){ return __int_as_float(x); }
__device__ __forceinline__ float readlane_f(float v, int l){
  return i2f(__builtin_amdgcn_readlane(f2i(v), l));
}
template<int CTRL, int RMASK>
__device__ __forceinline__ float dpp_add(float x){
  return x + i2f(__builtin_amdgcn_update_dpp(0, f2i(x), CTRL, RMASK, 0xf, true));
}
__device__ __forceinline__ float wave_sum_dpp(float x){
  x = dpp_add<0x111, 0xf>(x);
  x = dpp_add<0x112, 0xf>(x);
  x = dpp_add<0x114, 0xf>(x);
  x = dpp_add<0x118, 0xf>(x);
  x = dpp_add<0x142, 0xa>(x);
  x = dpp_add<0x143, 0xc>(x);
  return readlane_f(x, 63);
}
__device__ __forceinline__ float wave_sum(float v){
  #pragma unroll
  for (int m = 1; m < 64; m <<= 1) v += __shfl_xor(v, m, 64);
  return v;
}
__device__ __forceinline__ float wave_max(float v){
  #pragma unroll
  for (int m = 1; m < 64; m <<= 1) v = fmaxf(v, __shfl_xor(v, m, 64));
  return v;
}
#define BARRIER() asm volatile("s_waitcnt lgkmcnt(0)\n\ts_barrier" ::: "memory")

// --- kernel 0: invvar = exp(-logv), cs[s] = sum_d logv + D*log(2pi)
__global__ void prep_kernel(const float* __restrict__ logv,
                            float* __restrict__ iv, float* __restrict__ cs){
  int gid = blockIdx.x * blockDim.x + threadIdx.x;
  if (gid < SS * DD) iv[gid] = __expf(-logv[gid]);
  if (gid < SS){
    float s = 0.f;
    #pragma unroll
    for (int d = 0; d < DD; ++d) s += logv[gid * DD + d];
    cs[gid] = s + (float)DD * 1.8378770664093453f;
  }
}

// --- kernel 1: slx[t,b,s] = lx - rowmax(lx)
__global__ __launch_bounds__(256) void logpx_kernel(
    const float* __restrict__ x, const float* __restrict__ mu,
    const float* __restrict__ iv, const float* __restrict__ cs,
    float* __restrict__ slx_out){
  const int lane = threadIdx.x & 63;
  const int w = threadIdx.x >> 6;
  const int row = blockIdx.x * 4 + w;
  const float* __restrict__ xp  = x  + row * DD;
  const float* __restrict__ mup = mu + lane * DD;
  const float* __restrict__ ivp = iv + lane * DD;
  float acc = 0.f;
  #pragma unroll
  for (int d = 0; d < DD; ++d){
    float diff = xp[d] - mup[d];
    acc = fmaf(diff * diff, ivp[d], acc);
  }
  float lx = -0.5f * (acc + cs[lane]);
  float mx = wave_max(lx);
  slx_out[row * SS + lane] = lx - mx;
}

// --- produce: NORMALIZED fp16 transition tiles. fwd: ET[j][i] (transposed);
// bwd: E[i][j]. grid = (f_cnt + b_cnt)*8 blocks (4 b's per block), 256 thr.
__global__ __launch_bounds__(256) void produce_kernel(
    const float* __restrict__ a, const float* __restrict__ w_base,
    const float* __restrict__ w_act, f16* __restrict__ ET,
    f16* __restrict__ E, int f_lo, int f_cnt, int b_lo, int b_cnt){
  const int lane = threadIdx.x & 63;   // row i
  const int wv = threadIdx.x >> 6;
  const int jb = wv * 16;              // 16-col chunk
  int blk = blockIdx.x;
  const bool isF = blk < f_cnt * 8;
  if (!isF) blk -= f_cnt * 8;
  const int rel = blk >> 3;
  const int b0 = (blk & 7) * 4;
  const int t = (isF ? f_lo : b_lo) + rel;

  float4 wb4[4], wa4[8][4];
  {
    const float4* wbp = (const float4*)(w_base + lane * SS + jb);
    #pragma unroll
    for (int q = 0; q < 4; ++q) wb4[q] = wbp[q];
    #pragma unroll
    for (int k = 0; k < 8; ++k){
      const float4* wap = (const float4*)(w_act + ((k * SS + lane) * SS) + jb);
      #pragma unroll
      for (int q = 0; q < 4; ++q) wa4[k][q] = wap[q];
    }
  }
  __shared__ float part[4][4][SS];
  #pragma unroll
  for (int g = 0; g < 4; ++g){
    const int b = b0 + g;
    float aa[8];
    const float* __restrict__ ap = a + (t * BB + b) * AA;
    #pragma unroll
    for (int k = 0; k < 8; ++k) aa[k] = ap[k];
    float4 uv[4];
    #pragma unroll
    for (int q = 0; q < 4; ++q){
      uv[q] = wb4[q];
      #pragma unroll
      for (int k = 0; k < 8; ++k){
        uv[q].x = fmaf(aa[k], wa4[k][q].x, uv[q].x);
        uv[q].y = fmaf(aa[k], wa4[k][q].y, uv[q].y);
        uv[q].z = fmaf(aa[k], wa4[k][q].z, uv[q].z);
        uv[q].w = fmaf(aa[k], wa4[k][q].w, uv[q].w);
      }
    }
    float ev[16]; float rpart = 0.f;
    #pragma unroll
    for (int q = 0; q < 4; ++q){
      ev[4*q+0] = __expf(uv[q].x); ev[4*q+1] = __expf(uv[q].y);
      ev[4*q+2] = __expf(uv[q].z); ev[4*q+3] = __expf(uv[q].w);
      rpart += ev[4*q+0] + ev[4*q+1] + ev[4*q+2] + ev[4*q+3];
    }
    part[g][wv][lane] = rpart;
    __syncthreads();
    float rs = part[g][0][lane] + part[g][1][lane]
             + part[g][2][lane] + part[g][3][lane];
    float rn = __builtin_amdgcn_rcpf(rs);
    const size_t tb = (size_t)(rel * BB + b) << 12;   // 4096 halves per tile
    if (isF){
      f16* __restrict__ dst = ET + tb;                // [j][i]
      #pragma unroll
      for (int c = 0; c < 16; ++c) dst[(jb + c) * SS + lane] = (f16)(ev[c] * rn);
    } else {
      f16* __restrict__ dst = E + tb + lane * SS + jb;  // [i][j]
      h8 o0, o1;
      #pragma unroll
      for (int k = 0; k < 8; ++k){ o0[k] = (f16)(ev[k] * rn); o1[k] = (f16)(ev[8+k] * rn); }
      *(h8*)(dst) = o0; *(h8*)(dst + 8) = o1;
    }
  }
}

// --- scan over one window: 64 blocks x 64 threads, 1 wave per chain, no LDS,
// no barriers, 3-buffer register ring (prefetch depth 2), fp16 tiles.
__global__ __launch_bounds__(64, 1) void scan_win_kernel(
    const float* __restrict__ slx, const float* __restrict__ mask,
    const float* __restrict__ il,
    const f16* __restrict__ ET, const f16* __restrict__ E,
    float* __restrict__ alpha, float* __restrict__ log_beta,
    float* __restrict__ fwd_u, float* __restrict__ bwd_b,
    int f_lo, int f_cnt, int b_lo, int b_cnt){
  const int lane = threadIdx.x;
  if (blockIdx.x < BB){
    // ---------------- FORWARD (lane = j; tile halves [j][i]) ----------------
    const int b = blockIdx.x;
    const h8* __restrict__ TB = (const h8*)ET + ((size_t)b << 9) + lane * 8;
    float u, c;
    if (f_lo == 0){
      u = __expf(slx[b * SS + lane] + il[lane]);
      c = __builtin_amdgcn_rcpf(wave_sum_dpp(u));
      alpha[b * SS + lane] = u * c;
    } else {
      u = fwd_u[b * SS + lane];
      c = __builtin_amdgcn_rcpf(wave_sum_dpp(u));
    }
    const float* __restrict__ sb = slx + b * SS + lane;
    float* __restrict__ ab = alpha + b * SS + lane;
    float slc = sb[(f_lo + 1) * (BB * SS)];
    float sl1 = sb[((f_lo + 2 <= TT - 1) ? (f_lo + 2) : (TT - 1)) * (BB * SS)];
    float sl2 = sb[((f_lo + 3 <= TT - 1) ? (f_lo + 3) : (TT - 1)) * (BB * SS)];
    h8 A[8], Bv[8], C[8];
    auto LD = [&](h8* buf, int r){
      const h8* __restrict__ p = TB + (size_t)r * (BB * 512);
      #pragma unroll
      for (int q = 0; q < 8; ++q) buf[q] = p[q];
    };
    auto FS = [&](h8* cur, int r){
      float a0 = 0.f, a1 = 0.f, a2 = 0.f, a3 = 0.f;
      #pragma unroll
      for (int q = 0; q < 8; ++q){
        a0 = fmaf(readlane_f(u, 8*q+0), (float)cur[q][0], a0);
        a1 = fmaf(readlane_f(u, 8*q+1), (float)cur[q][1], a1);
        a2 = fmaf(readlane_f(u, 8*q+2), (float)cur[q][2], a2);
        a3 = fmaf(readlane_f(u, 8*q+3), (float)cur[q][3], a3);
        a0 = fmaf(readlane_f(u, 8*q+4), (float)cur[q][4], a0);
        a1 = fmaf(readlane_f(u, 8*q+5), (float)cur[q][5], a1);
        a2 = fmaf(readlane_f(u, 8*q+6), (float)cur[q][6], a2);
        a3 = fmaf(readlane_f(u, 8*q+7), (float)cur[q][7], a3);
      }
      float S = (a0 + a1) + (a2 + a3);
      float un = __expf(slc) * fmaf(c, S, SEPS);       // alpha' (unnormalized)
      c = __builtin_amdgcn_rcpf(wave_sum_dpp(un));     // DPP, hides under next matvec
      u = un;
      ab[(f_lo + 1 + r) * (BB * SS)] = un * c;
      slc = sl1; sl1 = sl2;
      int tn = f_lo + 4 + r; if (tn > TT - 1) tn = TT - 1;
      sl2 = sb[tn * (BB * SS)];
    };
    LD(A, 0);
    LD(Bv, (f_cnt > 1) ? 1 : 0);
    int r = 0;
    for (;;){
      LD(C,  (r + 2 < f_cnt) ? r + 2 : f_cnt - 1); FS(A,  r); if (++r >= f_cnt) break;
      LD(A,  (r + 2 < f_cnt) ? r + 2 : f_cnt - 1); FS(Bv, r); if (++r >= f_cnt) break;
      LD(Bv, (r + 2 < f_cnt) ? r + 2 : f_cnt - 1); FS(C,  r); if (++r >= f_cnt) break;
    }
    fwd_u[b * SS + lane] = u;
  } else {
    // ---------------- BACKWARD (lane = i; tile halves [i][j]) ----------------
    const int bb = blockIdx.x - BB;
    const h8* __restrict__ TB = (const h8*)E + ((size_t)bb << 9) + lane * 8;
    float breg;
    if (b_lo + b_cnt == TT - 1){
      breg = 0.f;
      log_beta[(TT - 1) * (BB * SS) + bb * SS + lane] = 0.f;
    } else {
      breg = bwd_b[bb * SS + lane];
    }
    const float* __restrict__ sb = slx + bb * SS + lane;
    const float* __restrict__ mb = mask + bb;
    float* __restrict__ lb = log_beta + bb * SS + lane;
    const int r0 = b_cnt - 1;
    float slc = sb[(b_lo + r0 + 1) * (BB * SS)];
    float sl1 = sb[(b_lo + ((r0 - 1 > 0) ? r0 - 1 : 0) + 1) * (BB * SS)];
    float sl2 = sb[(b_lo + ((r0 - 2 > 0) ? r0 - 2 : 0) + 1) * (BB * SS)];
    float mc = mb[(b_lo + r0 + 1) * BB];
    float m1 = mb[(b_lo + ((r0 - 1 > 0) ? r0 - 1 : 0) + 1) * BB];
    float m2 = mb[(b_lo + ((r0 - 2 > 0) ? r0 - 2 : 0) + 1) * BB];
    h8 A[8], Bv[8], C[8];
    auto LD = [&](h8* buf, int r){
      const h8* __restrict__ p = TB + (size_t)r * (BB * 512);
      #pragma unroll
      for (int q = 0; q < 8; ++q) buf[q] = p[q];
    };
    auto BS_ = [&](h8* cur, int r){
      float wgt = __expf(slc + breg);                  // lane = j view
      float W = wave_sum_dpp(wgt);                     // overlaps matvec
      float rW = __builtin_amdgcn_rcpf(W);
      float a0 = 0.f, a1 = 0.f, a2 = 0.f, a3 = 0.f;
      #pragma unroll
      for (int q = 0; q < 8; ++q){
        a0 = fmaf(readlane_f(wgt, 8*q+0), (float)cur[q][0], a0);
        a1 = fmaf(readlane_f(wgt, 8*q+1), (float)cur[q][1], a1);
        a2 = fmaf(readlane_f(wgt, 8*q+2), (float)cur[q][2], a2);
        a3 = fmaf(readlane_f(wgt, 8*q+3), (float)cur[q][3], a3);
        a0 = fmaf(readlane_f(wgt, 8*q+4), (float)cur[q][4], a0);
        a1 = fmaf(readlane_f(wgt, 8*q+5), (float)cur[q][5], a1);
        a2 = fmaf(readlane_f(wgt, 8*q+6), (float)cur[q][6], a2);
        a3 = fmaf(readlane_f(wgt, 8*q+7), (float)cur[q][7], a3);
      }
      float dot = (a0 + a1) + (a2 + a3);
      // LSE shift-relative: v = log( sum_j (p_ij+EPS) wgt_j / W )
      float v = __logf(fmaf(dot, rW, EPSF));
      breg = (mc == 1.0f) ? v : 0.0f;
      lb[(b_lo + r) * (BB * SS)] = breg;
      slc = sl1; sl1 = sl2; mc = m1; m1 = m2;
      int rn2 = r - 3; if (rn2 < 0) rn2 = 0;
      sl2 = sb[(b_lo + rn2 + 1) * (BB * SS)];
      m2 = mb[(b_lo + rn2 + 1) * BB];
    };
    LD(A, r0);
    LD(Bv, (r0 - 1 > 0) ? r0 - 1 : 0);
    int r = r0;
    for (;;){
      LD(C,  (r - 2 > 0) ? r - 2 : 0); BS_(A,  r); if (--r < 0) break;
      LD(A,  (r - 2 > 0) ? r - 2 : 0); BS_(Bv, r); if (--r < 0) break;
      LD(Bv, (r - 2 > 0) ? r - 2 : 0); BS_(C,  r); if (--r < 0) break;
    }
    bwd_b[bb * SS + lane] = breg;
  }
}

// ================== R5 fallback scan (proven 402 us, 12.6 MB ws) ==================
__global__ __launch_bounds__(768) void scan_kernel(
    const float* __restrict__ slx, const float* __restrict__ mask,
    const float* __restrict__ il, const float* __restrict__ a,
    const float* __restrict__ w_base, const float* __restrict__ w_act,
    float* __restrict__ alpha, float* __restrict__ log_beta){
  const int lane = threadIdx.x & 63;
  const int w    = threadIdx.x >> 6;
  const bool is_fwd = (blockIdx.x < BB);
  const int b = is_fwd ? blockIdx.x : (blockIdx.x - BB);
  __shared__ __align__(16) float tile[3][SS * TS];
  __shared__ float rsp[3][8][SS];
  __shared__ float fpart[2][4][SS];
  __shared__ __align__(16) float aLDS[TT * AA];
  __shared__ float mLDS[TT];
  for (int idx = threadIdx.x; idx < TT * AA; idx += 768){
    int t = idx >> 3, k = idx & 7;
    aLDS[idx] = a[(t * BB + b) * AA + k];
  }
  for (int idx = threadIdx.x; idx < TT; idx += 768)
    mLDS[idx] = mask[idx * BB + b];
  if (w >= 4){
    const int pw = w - 4;
    const int jb = pw * 8;
    float wb[8], wa[8][8];
    #pragma unroll
    for (int jj = 0; jj < 8; ++jj){
      wb[jj] = w_base[lane * SS + jb + jj];
      #pragma unroll
      for (int k = 0; k < 8; ++k)
        wa[k][jj] = w_act[(k * SS + lane) * SS + jb + jj];
    }
    float aa[8], aan[8];
    {
      const int t0 = is_fwd ? 0 : (TT - 2);
      const float* __restrict__ ap = a + (t0 * BB + b) * AA;
      #pragma unroll
      for (int k = 0; k < 8; ++k) aa[k] = ap[k];
      const int t1 = is_fwd ? 1 : (TT - 3);
      const float* __restrict__ ap1 = a + (t1 * BB + b) * AA;
      #pragma unroll
      for (int k = 0; k < 8; ++k) aan[k] = ap1[k];
    }
    {
      float ev[8]; float racc = 0.f;
      #pragma unroll
      for (int jj = 0; jj < 8; ++jj){
        float u = wb[jj];
        #pragma unroll
        for (int k = 0; k < 8; ++k) u = fmaf(aa[k], wa[k][jj], u);
        ev[jj] = __expf(u); racc += ev[jj];
      }
      *(float4*)&tile[0][lane * TS + jb]     = make_float4(ev[0],ev[1],ev[2],ev[3]);
      *(float4*)&tile[0][lane * TS + jb + 4] = make_float4(ev[4],ev[5],ev[6],ev[7]);
      rsp[0][pw][lane] = racc;
    }
    BARRIER();
    int tw = 1;
    for (int s = 0; s < TT - 1; ++s){
      if (s <= TT - 3){
        #pragma unroll
        for (int k = 0; k < 8; ++k) aa[k] = aan[k];
        if (s + 1 <= TT - 3){
          const int tn = is_fwd ? (s + 2) : (TT - 4 - s);
          #pragma unroll
          for (int k = 0; k < 8; ++k) aan[k] = aLDS[tn * AA + k];
        }
        float ev[8]; float racc = 0.f;
        #pragma unroll
        for (int jj = 0; jj < 8; ++jj){
          float u = wb[jj];
          #pragma unroll
          for (int k = 0; k < 8; ++k) u = fmaf(aa[k], wa[k][jj], u);
          ev[jj] = __expf(u); racc += ev[jj];
        }
        *(float4*)&tile[tw][lane * TS + jb]     = make_float4(ev[0],ev[1],ev[2],ev[3]);
        *(float4*)&tile[tw][lane * TS + jb + 4] = make_float4(ev[4],ev[5],ev[6],ev[7]);
        rsp[tw][pw][lane] = racc;
        tw = (tw == 2) ? 0 : tw + 1;
      }
      BARRIER();
    }
  } else if (is_fwd){
    const int wb16 = __builtin_amdgcn_readfirstlane(w * 16);
    float u = __expf(slx[b * SS + lane] + il[lane]);
    float c = __builtin_amdgcn_rcpf(wave_sum_dpp(u));
    if (w == 0) alpha[b * SS + lane] = u * c;
    float slxn = slx[(BB + b) * SS + lane];
    float elxc = 0.f;
    BARRIER();
    int ts = 0;
    for (int s = 0; s < TT - 1; ++s){
      if (s > 0){
        const int fs = (s - 1) & 1;
        float S = (fpart[fs][0][lane] + fpart[fs][1][lane])
                + (fpart[fs][2][lane] + fpart[fs][3][lane]);
        u = elxc * fmaf(c, S, SEPS);
        c = __builtin_amdgcn_rcpf(wave_sum_dpp(u));
        if (w == 0) alpha[(s * BB + b) * SS + lane] = u * c;
      }
      float rs = ((rsp[ts][0][lane] + rsp[ts][1][lane]) + (rsp[ts][2][lane] + rsp[ts][3][lane]))
               + ((rsp[ts][4][lane] + rsp[ts][5][lane]) + (rsp[ts][6][lane] + rsp[ts][7][lane]));
      float va = u * __builtin_amdgcn_rcpf(rs);
      const float* __restrict__ tp = &tile[ts][0];
      float a0 = 0.f, a1 = 0.f, a2 = 0.f, a3 = 0.f;
      #pragma unroll
      for (int r = 0; r < 16; r += 4){
        a0 = fmaf(readlane_f(va, wb16 + r    ), tp[(wb16 + r    ) * TS + lane], a0);
        a1 = fmaf(readlane_f(va, wb16 + r + 1), tp[(wb16 + r + 1) * TS + lane], a1);
        a2 = fmaf(readlane_f(va, wb16 + r + 2), tp[(wb16 + r + 2) * TS + lane], a2);
        a3 = fmaf(readlane_f(va, wb16 + r + 3), tp[(wb16 + r + 3) * TS + lane], a3);
      }
      fpart[s & 1][w][lane] = (a0 + a1) + (a2 + a3);
      elxc = __expf(slxn);
      if (s + 2 <= TT - 1) slxn = slx[((s + 2) * BB + b) * SS + lane];
      ts = (ts == 2) ? 0 : ts + 1;
      BARRIER();
    }
    {
      const int fs = (TT - 2) & 1;
      float S = (fpart[fs][0][lane] + fpart[fs][1][lane])
              + (fpart[fs][2][lane] + fpart[fs][3][lane]);
      u = elxc * fmaf(c, S, SEPS);
      c = __builtin_amdgcn_rcpf(wave_sum_dpp(u));
      if (w == 0) alpha[((TT - 1) * BB + b) * SS + lane] = u * c;
    }
  } else {
    const int wb16 = __builtin_amdgcn_readfirstlane(w * 16);
    float breg = 0.f, rWc = 1.f;
    if (w == 0) log_beta[((TT - 1) * BB + b) * SS + lane] = 0.f;
    float slxc = slx[((TT - 1) * BB + b) * SS + lane];
    float mprev = 1.f;
    BARRIER();
    int ts = 0, pts = 2;
    for (int s = 0; s < TT - 1; ++s){
      if (s > 0){
        const int fs = (s - 1) & 1;
        float eh = (fpart[fs][0][lane] + fpart[fs][1][lane])
                 + (fpart[fs][2][lane] + fpart[fs][3][lane]);
        float rsv = ((rsp[pts][0][lane] + rsp[pts][1][lane]) + (rsp[pts][2][lane] + rsp[pts][3][lane]))
                  + ((rsp[pts][4][lane] + rsp[pts][5][lane]) + (rsp[pts][6][lane] + rsp[pts][7][lane]));
        float v = __logf(fmaf(eh * __builtin_amdgcn_rcpf(rsv), rWc, EPSF));
        breg = (mprev == 1.0f) ? v : 0.0f;
        if (w == 0) log_beta[((TT - 1 - s) * BB + b) * SS + lane] = breg;
      }
      float wgt = __expf(slxc + breg);
      float W = wave_sum_dpp(wgt);
      rWc = __builtin_amdgcn_rcpf(W);
      const float* __restrict__ tp = &tile[ts][lane * TS + wb16];
      float4 e0 = *(const float4*)(tp);
      float4 e1 = *(const float4*)(tp + 4);
      float4 e2 = *(const float4*)(tp + 8);
      float4 e3 = *(const float4*)(tp + 12);
      float a0 = 0.f, a1 = 0.f, a2 = 0.f, a3 = 0.f;
      a0 = fmaf(readlane_f(wgt, wb16 + 0),  e0.x, a0);
      a1 = fmaf(readlane_f(wgt, wb16 + 1),  e0.y, a1);
      a2 = fmaf(readlane_f(wgt, wb16 + 2),  e0.z, a2);
      a3 = fmaf(readlane_f(wgt, wb16 + 3),  e0.w, a3);
      a0 = fmaf(readlane_f(wgt, wb16 + 4),  e1.x, a0);
      a1 = fmaf(readlane_f(wgt, wb16 + 5),  e1.y, a1);
      a2 = fmaf(readlane_f(wgt, wb16 + 6),  e1.z, a2);
      a3 = fmaf(readlane_f(wgt, wb16 + 7),  e1.w, a3);
      a0 = fmaf(readlane_f(wgt, wb16 + 8),  e2.x, a0);
      a1 = fmaf(readlane_f(wgt, wb16 + 9),  e2.y, a1);
      a2 = fmaf(readlane_f(wgt, wb16 + 10), e2.z, a2);
      a3 = fmaf(readlane_f(wgt, wb16 + 11), e2.w, a3);
      a0 = fmaf(readlane_f(wgt, wb16 + 12), e3.x, a0);
      a1 = fmaf(readlane_f(wgt, wb16 + 13), e3.y, a1);
      a2 = fmaf(readlane_f(wgt, wb16 + 14), e3.z, a2);
      a3 = fmaf(readlane_f(wgt, wb16 + 15), e3.w, a3);
      fpart[s & 1][w][lane] = (a0 + a1) + (a2 + a3);
      mprev = mLDS[TT - 1 - s];
      if (s <= TT - 3) slxc = slx[((TT - 2 - s) * BB + b) * SS + lane];
      pts = ts; ts = (ts == 2) ? 0 : ts + 1;
      BARRIER();
    }
    {
      const int fs = (TT - 2) & 1;
      float eh = (fpart[fs][0][lane] + fpart[fs][1][lane])
               + (fpart[fs][2][lane] + fpart[fs][3][lane]);
      float rsv = ((rsp[pts][0][lane] + rsp[pts][1][lane]) + (rsp[pts][2][lane] + rsp[pts][3][lane]))
                + ((rsp[pts][4][lane] + rsp[pts][5][lane]) + (rsp[pts][6][lane] + rsp[pts][7][lane]));
      float v = __logf(fmaf(eh * __builtin_amdgcn_rcpf(rsv), rWc, EPSF));
      breg = (mprev == 1.0f) ? v : 0.0f;
      if (w == 0) log_beta[b * SS + lane] = breg;
    }
  }
}

// --- q_z = softmax(log(alpha+EPS) + log_beta)
__global__ __launch_bounds__(256) void qz_kernel(
    const float* __restrict__ alpha, const float* __restrict__ log_beta,
    float* __restrict__ out){
  const int lane = threadIdx.x & 63;
  const int w = threadIdx.x >> 6;
  const int row = blockIdx.x * 4 + w;
  float v = __logf(alpha[row * SS + lane] + EPSF) + log_beta[row * SS + lane];
  float mx = wave_max(v);
  float e = __expf(v - mx);
  float sm = wave_sum(e);
  out[row * SS + lane] = e * __builtin_amdgcn_rcpf(sm);
}

extern "C" void kernel_launch(void* const* d_in, const int* in_sizes, int n_in,
                              void* d_out, int out_size, void* d_ws, size_t ws_size,
                              hipStream_t stream){
  const float* x      = (const float*)d_in[0];
  const float* a      = (const float*)d_in[1];
  const float* mask   = (const float*)d_in[2];
  const float* mu     = (const float*)d_in[3];
  const float* logv   = (const float*)d_in[4];
  const float* il     = (const float*)d_in[5];
  const float* w_base = (const float*)d_in[6];
  const float* w_act  = (const float*)d_in[7];
  float* out = (float*)d_out;

  float* ws = (float*)d_ws;
  const size_t TBS = (size_t)TT * BB * SS;
  float* iv       = ws;                   // 2048 (+cs, pad to 4096)
  float* cs       = ws + 2048;
  float* slx      = ws + 4096;
  float* alpha    = slx + TBS;
  float* log_beta = alpha + TBS;
  float* fwd_u    = log_beta + TBS;       // 2048
  float* bwd_b    = fwd_u + 2048;         // 2048 (pad to 8192)
  const size_t base = 4096 + 3 * TBS + 8192;   // floats
  f16* ET = (f16*)(ws + base);

  // choose largest window W whose two fp16 tile buffers fit
  int W = 0;
  const int tiers[6] = {511, 384, 256, 128, 64, 32};
  for (int i = 0; i < 6; ++i){
    const size_t need = base * 4 + 2 * (size_t)tiers[i] * BB * 4096 * 2;
    if (need <= ws_size){ W = tiers[i]; break; }
  }

  prep_kernel<<<8, 256, 0, stream>>>(logv, iv, cs);
  logpx_kernel<<<TT * BB / 4, 256, 0, stream>>>(x, mu, iv, cs, slx);
  if (W > 0){
    f16* E = ET + (size_t)W * BB * 4096;
    const int nw = (TT - 1 + W - 1) / W;
    for (int k = 0; k < nw; ++k){
      const int f_lo = k * W;
      const int f_cnt = ((TT - 1) - f_lo < W) ? ((TT - 1) - f_lo) : W;
      const int b_hi = (TT - 1) - k * W;
      const int b_lo = (b_hi - W > 0) ? (b_hi - W) : 0;
      const int b_cnt = b_hi - b_lo;
      produce_kernel<<<(f_cnt + b_cnt) * 8, 256, 0, stream>>>(
          a, w_base, w_act, ET, E, f_lo, f_cnt, b_lo, b_cnt);
      scan_win_kernel<<<2 * BB, 64, 0, stream>>>(
          slx, mask, il, ET, E, alpha, log_beta, fwd_u, bwd_b,
          f_lo, f_cnt, b_lo, b_cnt);
    }
  } else {
    scan_kernel<<<2 * BB, 768, 0, stream>>>(slx, mask, il, a, w_base, w_act,
                                            alpha, log_beta);
  }
  qz_kernel<<<TT * BB / 4, 256, 0, stream>>>(alpha, log_beta, out);
}

// Round 8
// 694.493 us; speedup vs baseline: 1.3554x; 1.0529x over previous
//
#include <hip/hip_runtime.h>
#include <math.h>

#define TT 512
#define BB 32
#define SS 64
#define AA 8
#define DD 32
#define EPSF 1e-6f
#define SEPS (64.0f * 1e-6f)   // reference adds EPS under the 64-term i-sum
#define TS 68                  // (fallback kernel) tile row stride

typedef _Float16 f16;
typedef f16 h8 __attribute__((ext_vector_type(8)));   // 16 B = 8 halves

__device__ __forceinline__ int   f2i(float x){ return __float_as_int(x); }
__device__ __forceinline__ float i2f(int x){ return __int_as_float(x); }
__device__ __forceinline__ float readlane_f(float v, int l){
  return i2f(__builtin_amdgcn_readlane(f2i(v), l));
}
template<int CTRL, int RMASK>
__device__ __forceinline__ float dpp_add(float x){
  return x + i2f(__builtin_amdgcn_update_dpp(0, f2i(x), CTRL, RMASK, 0xf, true));
}
__device__ __forceinline__ float wave_sum_dpp(float x){
  x = dpp_add<0x111, 0xf>(x);
  x = dpp_add<0x112, 0xf>(x);
  x = dpp_add<0x114, 0xf>(x);
  x = dpp_add<0x118, 0xf>(x);
  x = dpp_add<0x142, 0xa>(x);
  x = dpp_add<0x143, 0xc>(x);
  return readlane_f(x, 63);
}
__device__ __forceinline__ float wave_sum(float v){
  #pragma unroll
  for (int m = 1; m < 64; m <<= 1) v += __shfl_xor(v, m, 64);
  return v;
}
__device__ __forceinline__ float wave_max(float v){
  #pragma unroll
  for (int m = 1; m < 64; m <<= 1) v = fmaxf(v, __shfl_xor(v, m, 64));
  return v;
}
#define BARRIER() asm volatile("s_waitcnt lgkmcnt(0)\n\ts_barrier" ::: "memory")

// --- kernel 0
__global__ void prep_kernel(const float* __restrict__ logv,
                            float* __restrict__ iv, float* __restrict__ cs){
  int gid = blockIdx.x * blockDim.x + threadIdx.x;
  if (gid < SS * DD) iv[gid] = __expf(-logv[gid]);
  if (gid < SS){
    float s = 0.f;
    #pragma unroll
    for (int d = 0; d < DD; ++d) s += logv[gid * DD + d];
    cs[gid] = s + (float)DD * 1.8378770664093453f;
  }
}

// --- kernel 1: slx = lx - rowmax
__global__ __launch_bounds__(256) void logpx_kernel(
    const float* __restrict__ x, const float* __restrict__ mu,
    const float* __restrict__ iv, const float* __restrict__ cs,
    float* __restrict__ slx_out){
  const int lane = threadIdx.x & 63;
  const int w = threadIdx.x >> 6;
  const int row = blockIdx.x * 4 + w;
  const float* __restrict__ xp  = x  + row * DD;
  const float* __restrict__ mup = mu + lane * DD;
  const float* __restrict__ ivp = iv + lane * DD;
  float acc = 0.f;
  #pragma unroll
  for (int d = 0; d < DD; ++d){
    float diff = xp[d] - mup[d];
    acc = fmaf(diff * diff, ivp[d], acc);
  }
  float lx = -0.5f * (acc + cs[lane]);
  float mx = wave_max(lx);
  slx_out[row * SS + lane] = lx - mx;
}

// --- produce: normalized fp16 tiles. fwd: ET[j][i] via LDS transpose (coalesced
// stores); bwd: E[i][j] direct. grid = (f_cnt+b_cnt)*8 blocks (4 b's each).
__global__ __launch_bounds__(256) void produce_kernel(
    const float* __restrict__ a, const float* __restrict__ w_base,
    const float* __restrict__ w_act, f16* __restrict__ ET,
    f16* __restrict__ E, int f_lo, int f_cnt, int b_lo, int b_cnt){
  const int lane = threadIdx.x & 63;   // row i
  const int wv = threadIdx.x >> 6;
  const int jb = wv * 16;
  int blk = blockIdx.x;
  const bool isF = blk < f_cnt * 8;
  if (!isF) blk -= f_cnt * 8;
  const int rel = blk >> 3;
  const int b0 = (blk & 7) * 4;
  const int t = (isF ? f_lo : b_lo) + rel;

  float4 wb4[4], wa4[8][4];
  {
    const float4* wbp = (const float4*)(w_base + lane * SS + jb);
    #pragma unroll
    for (int q = 0; q < 4; ++q) wb4[q] = wbp[q];
    #pragma unroll
    for (int k = 0; k < 8; ++k){
      const float4* wap = (const float4*)(w_act + ((k * SS + lane) * SS) + jb);
      #pragma unroll
      for (int q = 0; q < 4; ++q) wa4[k][q] = wap[q];
    }
  }
  __shared__ float part[4][4][SS];
  __shared__ f16 tr[4][SS][SS + 8];    // [g][j][i], padded
  #pragma unroll
  for (int g = 0; g < 4; ++g){
    const int b = b0 + g;
    float aa[8];
    const float* __restrict__ ap = a + (t * BB + b) * AA;
    #pragma unroll
    for (int k = 0; k < 8; ++k) aa[k] = ap[k];
    float4 uv[4];
    #pragma unroll
    for (int q = 0; q < 4; ++q){
      uv[q] = wb4[q];
      #pragma unroll
      for (int k = 0; k < 8; ++k){
        uv[q].x = fmaf(aa[k], wa4[k][q].x, uv[q].x);
        uv[q].y = fmaf(aa[k], wa4[k][q].y, uv[q].y);
        uv[q].z = fmaf(aa[k], wa4[k][q].z, uv[q].z);
        uv[q].w = fmaf(aa[k], wa4[k][q].w, uv[q].w);
      }
    }
    float ev[16]; float rpart = 0.f;
    #pragma unroll
    for (int q = 0; q < 4; ++q){
      ev[4*q+0] = __expf(uv[q].x); ev[4*q+1] = __expf(uv[q].y);
      ev[4*q+2] = __expf(uv[q].z); ev[4*q+3] = __expf(uv[q].w);
      rpart += ev[4*q+0] + ev[4*q+1] + ev[4*q+2] + ev[4*q+3];
    }
    part[g][wv][lane] = rpart;
    __syncthreads();                                  // A: partials visible
    float rs = part[g][0][lane] + part[g][1][lane]
             + part[g][2][lane] + part[g][3][lane];
    float rn = __builtin_amdgcn_rcpf(rs);
    const size_t tb = (size_t)(rel * BB + b) << 12;   // 4096 halves per tile
    if (isF){
      #pragma unroll
      for (int c = 0; c < 16; ++c) tr[g][jb + c][lane] = (f16)(ev[c] * rn);
      __syncthreads();                                // B: transpose staged
      const int j = threadIdx.x >> 2, seg = threadIdx.x & 3;
      h8 v0 = *(const h8*)&tr[g][j][seg * 16];
      h8 v1 = *(const h8*)&tr[g][j][seg * 16 + 8];
      f16* __restrict__ dst = ET + tb + j * SS + seg * 16;
      *(h8*)dst = v0; *(h8*)(dst + 8) = v1;           // coalesced 32 B/thread
    } else {
      f16* __restrict__ dst = E + tb + lane * SS + jb;
      h8 o0, o1;
      #pragma unroll
      for (int k = 0; k < 8; ++k){ o0[k] = (f16)(ev[k] * rn); o1[k] = (f16)(ev[8+k] * rn); }
      *(h8*)(dst) = o0; *(h8*)(dst + 8) = o1;
      __syncthreads();                                // keep barrier count uniform
    }
  }
}

// matvec helper: by-value h8 keeps everything in VGPRs; base is compile-time.
__device__ __forceinline__ void mv8(float& x0, float& x1, float& x2, float& x3,
                                    float src, h8 bv, int base){
  x0 = fmaf(readlane_f(src, base + 0), (float)bv[0], x0);
  x1 = fmaf(readlane_f(src, base + 1), (float)bv[1], x1);
  x2 = fmaf(readlane_f(src, base + 2), (float)bv[2], x2);
  x3 = fmaf(readlane_f(src, base + 3), (float)bv[3], x3);
  x0 = fmaf(readlane_f(src, base + 4), (float)bv[4], x0);
  x1 = fmaf(readlane_f(src, base + 5), (float)bv[5], x1);
  x2 = fmaf(readlane_f(src, base + 6), (float)bv[6], x2);
  x3 = fmaf(readlane_f(src, base + 7), (float)bv[7], x3);
}

#define DECLB(N) h8 N##0, N##1, N##2, N##3, N##4, N##5, N##6, N##7;
#define LDB(TB, N, rr) { const h8* __restrict__ _p = (TB) + (size_t)(rr) * (BB * 512); \
  N##0=_p[0]; N##1=_p[1]; N##2=_p[2]; N##3=_p[3]; N##4=_p[4]; N##5=_p[5]; N##6=_p[6]; N##7=_p[7]; }
#define MATVEC(N, SRC, P0, P1, P2, P3) \
  mv8(P0,P1,P2,P3,SRC,N##0,0);  mv8(P0,P1,P2,P3,SRC,N##1,8); \
  mv8(P0,P1,P2,P3,SRC,N##2,16); mv8(P0,P1,P2,P3,SRC,N##3,24); \
  mv8(P0,P1,P2,P3,SRC,N##4,32); mv8(P0,P1,P2,P3,SRC,N##5,40); \
  mv8(P0,P1,P2,P3,SRC,N##6,48); mv8(P0,P1,P2,P3,SRC,N##7,56);

// --- scan over one window: 64 blocks x 64 threads, register ring depth-2.
__global__ __launch_bounds__(64, 1) void scan_win_kernel(
    const float* __restrict__ slx, const float* __restrict__ mask,
    const float* __restrict__ il,
    const f16* __restrict__ ET, const f16* __restrict__ E,
    float* __restrict__ alpha, float* __restrict__ log_beta,
    float* __restrict__ fwd_u, float* __restrict__ bwd_b,
    int f_lo, int f_cnt, int b_lo, int b_cnt){
  const int lane = threadIdx.x;
  if (blockIdx.x < BB){
    // ---------------- FORWARD (lane = j; ET[j][i]) ----------------
    const int b = blockIdx.x;
    const h8* __restrict__ TBF = (const h8*)ET + ((size_t)b << 9) + lane * 8;
    float u, c;
    if (f_lo == 0){
      u = __expf(slx[b * SS + lane] + il[lane]);
      c = __builtin_amdgcn_rcpf(wave_sum_dpp(u));
      alpha[b * SS + lane] = u * c;
    } else {
      u = fwd_u[b * SS + lane];
      c = __builtin_amdgcn_rcpf(wave_sum_dpp(u));
    }
    const float* __restrict__ sb = slx + b * SS + lane;
    float* __restrict__ ab = alpha + b * SS + lane;
    float slc = sb[(f_lo + 1) * (BB * SS)];
    float sl1 = sb[((f_lo + 2 <= TT - 1) ? (f_lo + 2) : (TT - 1)) * (BB * SS)];
    float sl2 = sb[((f_lo + 3 <= TT - 1) ? (f_lo + 3) : (TT - 1)) * (BB * SS)];
    DECLB(A) DECLB(B) DECLB(C)
#define FSTEP(N, rr) { \
      float p0=0.f,p1=0.f,p2=0.f,p3=0.f; \
      MATVEC(N, u, p0, p1, p2, p3) \
      float S = (p0 + p1) + (p2 + p3); \
      float un = __expf(slc) * fmaf(c, S, SEPS); \
      c = __builtin_amdgcn_rcpf(wave_sum_dpp(un)); \
      u = un; \
      ab[(f_lo + 1 + (rr)) * (BB * SS)] = un * c; \
      slc = sl1; sl1 = sl2; \
      { int tn = f_lo + 4 + (rr); if (tn > TT - 1) tn = TT - 1; \
        sl2 = sb[tn * (BB * SS)]; } }
    LDB(TBF, A, 0);
    LDB(TBF, B, (f_cnt > 1) ? 1 : 0);
    int r = 0;
    for (;;){
      LDB(TBF, C, (r + 2 < f_cnt) ? r + 2 : f_cnt - 1); FSTEP(A, r); if (++r >= f_cnt) break;
      LDB(TBF, A, (r + 2 < f_cnt) ? r + 2 : f_cnt - 1); FSTEP(B, r); if (++r >= f_cnt) break;
      LDB(TBF, B, (r + 2 < f_cnt) ? r + 2 : f_cnt - 1); FSTEP(C, r); if (++r >= f_cnt) break;
    }
#undef FSTEP
    fwd_u[b * SS + lane] = u;
  } else {
    // ---------------- BACKWARD (lane = i; E[i][j]) ----------------
    const int bb = blockIdx.x - BB;
    const h8* __restrict__ TBB = (const h8*)E + ((size_t)bb << 9) + lane * 8;
    float breg;
    if (b_lo + b_cnt == TT - 1){
      breg = 0.f;
      log_beta[(TT - 1) * (BB * SS) + bb * SS + lane] = 0.f;
    } else {
      breg = bwd_b[bb * SS + lane];
    }
    const float* __restrict__ sb = slx + bb * SS + lane;
    const float* __restrict__ mb = mask + bb;
    float* __restrict__ lb = log_beta + bb * SS + lane;
    const int r0 = b_cnt - 1;
    float slc = sb[(b_lo + r0 + 1) * (BB * SS)];
    float sl1 = sb[(b_lo + ((r0 - 1 > 0) ? r0 - 1 : 0) + 1) * (BB * SS)];
    float sl2 = sb[(b_lo + ((r0 - 2 > 0) ? r0 - 2 : 0) + 1) * (BB * SS)];
    float mc = mb[(b_lo + r0 + 1) * BB];
    float m1 = mb[(b_lo + ((r0 - 1 > 0) ? r0 - 1 : 0) + 1) * BB];
    float m2 = mb[(b_lo + ((r0 - 2 > 0) ? r0 - 2 : 0) + 1) * BB];
    DECLB(A) DECLB(B) DECLB(C)
#define BSTEP(N, rr) { \
      float wgt = __expf(slc + breg); \
      float W = wave_sum_dpp(wgt); \
      float rW = __builtin_amdgcn_rcpf(W); \
      float p0=0.f,p1=0.f,p2=0.f,p3=0.f; \
      MATVEC(N, wgt, p0, p1, p2, p3) \
      float dot = (p0 + p1) + (p2 + p3); \
      float v = __logf(fmaf(dot, rW, EPSF)); \
      breg = (mc == 1.0f) ? v : 0.0f; \
      lb[(b_lo + (rr)) * (BB * SS)] = breg; \
      slc = sl1; sl1 = sl2; mc = m1; m1 = m2; \
      { int rn2 = (rr) - 3; if (rn2 < 0) rn2 = 0; \
        sl2 = sb[(b_lo + rn2 + 1) * (BB * SS)]; \
        m2  = mb[(b_lo + rn2 + 1) * BB]; } }
    LDB(TBB, A, r0);
    LDB(TBB, B, (r0 - 1 > 0) ? r0 - 1 : 0);
    int r = r0;
    for (;;){
      LDB(TBB, C, (r - 2 > 0) ? r - 2 : 0); BSTEP(A, r); if (--r < 0) break;
      LDB(TBB, A, (r - 2 > 0) ? r - 2 : 0); BSTEP(B, r); if (--r < 0) break;
      LDB(TBB, B, (r - 2 > 0) ? r - 2 : 0); BSTEP(C, r); if (--r < 0) break;
    }
#undef BSTEP
    bwd_b[bb * SS + lane] = breg;
  }
}

// ================== R5 fallback scan (proven 402 us, 12.6 MB ws) ==================
__global__ __launch_bounds__(768) void scan_kernel(
    const float* __restrict__ slx, const float* __restrict__ mask,
    const float* __restrict__ il, const float* __restrict__ a,
    const float* __restrict__ w_base, const float* __restrict__ w_act,
    float* __restrict__ alpha, float* __restrict__ log_beta){
  const int lane = threadIdx.x & 63;
  const int w    = threadIdx.x >> 6;
  const bool is_fwd = (blockIdx.x < BB);
  const int b = is_fwd ? blockIdx.x : (blockIdx.x - BB);
  __shared__ __align__(16) float tile[3][SS * TS];
  __shared__ float rsp[3][8][SS];
  __shared__ float fpart[2][4][SS];
  __shared__ __align__(16) float aLDS[TT * AA];
  __shared__ float mLDS[TT];
  for (int idx = threadIdx.x; idx < TT * AA; idx += 768){
    int t = idx >> 3, k = idx & 7;
    aLDS[idx] = a[(t * BB + b) * AA + k];
  }
  for (int idx = threadIdx.x; idx < TT; idx += 768)
    mLDS[idx] = mask[idx * BB + b];
  if (w >= 4){
    const int pw = w - 4;
    const int jb = pw * 8;
    float wb[8], wa[8][8];
    #pragma unroll
    for (int jj = 0; jj < 8; ++jj){
      wb[jj] = w_base[lane * SS + jb + jj];
      #pragma unroll
      for (int k = 0; k < 8; ++k)
        wa[k][jj] = w_act[(k * SS + lane) * SS + jb + jj];
    }
    float aa[8], aan[8];
    {
      const int t0 = is_fwd ? 0 : (TT - 2);
      const float* __restrict__ ap = a + (t0 * BB + b) * AA;
      #pragma unroll
      for (int k = 0; k < 8; ++k) aa[k] = ap[k];
      const int t1 = is_fwd ? 1 : (TT - 3);
      const float* __restrict__ ap1 = a + (t1 * BB + b) * AA;
      #pragma unroll
      for (int k = 0; k < 8; ++k) aan[k] = ap1[k];
    }
    {
      float ev[8]; float racc = 0.f;
      #pragma unroll
      for (int jj = 0; jj < 8; ++jj){
        float u = wb[jj];
        #pragma unroll
        for (int k = 0; k < 8; ++k) u = fmaf(aa[k], wa[k][jj], u);
        ev[jj] = __expf(u); racc += ev[jj];
      }
      *(float4*)&tile[0][lane * TS + jb]     = make_float4(ev[0],ev[1],ev[2],ev[3]);
      *(float4*)&tile[0][lane * TS + jb + 4] = make_float4(ev[4],ev[5],ev[6],ev[7]);
      rsp[0][pw][lane] = racc;
    }
    BARRIER();
    int tw = 1;
    for (int s = 0; s < TT - 1; ++s){
      if (s <= TT - 3){
        #pragma unroll
        for (int k = 0; k < 8; ++k) aa[k] = aan[k];
        if (s + 1 <= TT - 3){
          const int tn = is_fwd ? (s + 2) : (TT - 4 - s);
          #pragma unroll
          for (int k = 0; k < 8; ++k) aan[k] = aLDS[tn * AA + k];
        }
        float ev[8]; float racc = 0.f;
        #pragma unroll
        for (int jj = 0; jj < 8; ++jj){
          float u = wb[jj];
          #pragma unroll
          for (int k = 0; k < 8; ++k) u = fmaf(aa[k], wa[k][jj], u);
          ev[jj] = __expf(u); racc += ev[jj];
        }
        *(float4*)&tile[tw][lane * TS + jb]     = make_float4(ev[0],ev[1],ev[2],ev[3]);
        *(float4*)&tile[tw][lane * TS + jb + 4] = make_float4(ev[4],ev[5],ev[6],ev[7]);
        rsp[tw][pw][lane] = racc;
        tw = (tw == 2) ? 0 : tw + 1;
      }
      BARRIER();
    }
  } else if (is_fwd){
    const int wb16 = __builtin_amdgcn_readfirstlane(w * 16);
    float u = __expf(slx[b * SS + lane] + il[lane]);
    float c = __builtin_amdgcn_rcpf(wave_sum_dpp(u));
    if (w == 0) alpha[b * SS + lane] = u * c;
    float slxn = slx[(BB + b) * SS + lane];
    float elxc = 0.f;
    BARRIER();
    int ts = 0;
    for (int s = 0; s < TT - 1; ++s){
      if (s > 0){
        const int fs = (s - 1) & 1;
        float S = (fpart[fs][0][lane] + fpart[fs][1][lane])
                + (fpart[fs][2][lane] + fpart[fs][3][lane]);
        u = elxc * fmaf(c, S, SEPS);
        c = __builtin_amdgcn_rcpf(wave_sum_dpp(u));
        if (w == 0) alpha[(s * BB + b) * SS + lane] = u * c;
      }
      float rs = ((rsp[ts][0][lane] + rsp[ts][1][lane]) + (rsp[ts][2][lane] + rsp[ts][3][lane]))
               + ((rsp[ts][4][lane] + rsp[ts][5][lane]) + (rsp[ts][6][lane] + rsp[ts][7][lane]));
      float va = u * __builtin_amdgcn_rcpf(rs);
      const float* __restrict__ tp = &tile[ts][0];
      float a0 = 0.f, a1 = 0.f, a2 = 0.f, a3 = 0.f;
      #pragma unroll
      for (int r = 0; r < 16; r += 4){
        a0 = fmaf(readlane_f(va, wb16 + r    ), tp[(wb16 + r    ) * TS + lane], a0);
        a1 = fmaf(readlane_f(va, wb16 + r + 1), tp[(wb16 + r + 1) * TS + lane], a1);
        a2 = fmaf(readlane_f(va, wb16 + r + 2), tp[(wb16 + r + 2) * TS + lane], a2);
        a3 = fmaf(readlane_f(va, wb16 + r + 3), tp[(wb16 + r + 3) * TS + lane], a3);
      }
      fpart[s & 1][w][lane] = (a0 + a1) + (a2 + a3);
      elxc = __expf(slxn);
      if (s + 2 <= TT - 1) slxn = slx[((s + 2) * BB + b) * SS + lane];
      ts = (ts == 2) ? 0 : ts + 1;
      BARRIER();
    }
    {
      const int fs = (TT - 2) & 1;
      float S = (fpart[fs][0][lane] + fpart[fs][1][lane])
              + (fpart[fs][2][lane] + fpart[fs][3][lane]);
      u = elxc * fmaf(c, S, SEPS);
      c = __builtin_amdgcn_rcpf(wave_sum_dpp(u));
      if (w == 0) alpha[((TT - 1) * BB + b) * SS + lane] = u * c;
    }
  } else {
    const int wb16 = __builtin_amdgcn_readfirstlane(w * 16);
    float breg = 0.f, rWc = 1.f;
    if (w == 0) log_beta[((TT - 1) * BB + b) * SS + lane] = 0.f;
    float slxc = slx[((TT - 1) * BB + b) * SS + lane];
    float mprev = 1.f;
    BARRIER();
    int ts = 0, pts = 2;
    for (int s = 0; s < TT - 1; ++s){
      if (s > 0){
        const int fs = (s - 1) & 1;
        float eh = (fpart[fs][0][lane] + fpart[fs][1][lane])
                 + (fpart[fs][2][lane] + fpart[fs][3][lane]);
        float rsv = ((rsp[pts][0][lane] + rsp[pts][1][lane]) + (rsp[pts][2][lane] + rsp[pts][3][lane]))
                  + ((rsp[pts][4][lane] + rsp[pts][5][lane]) + (rsp[pts][6][lane] + rsp[pts][7][lane]));
        float v = __logf(fmaf(eh * __builtin_amdgcn_rcpf(rsv), rWc, EPSF));
        breg = (mprev == 1.0f) ? v : 0.0f;
        if (w == 0) log_beta[((TT - 1 - s) * BB + b) * SS + lane] = breg;
      }
      float wgt = __expf(slxc + breg);
      float W = wave_sum_dpp(wgt);
      rWc = __builtin_amdgcn_rcpf(W);
      const float* __restrict__ tp = &tile[ts][lane * TS + wb16];
      float4 e0 = *(const float4*)(tp);
      float4 e1 = *(const float4*)(tp + 4);
      float4 e2 = *(const float4*)(tp + 8);
      float4 e3 = *(const float4*)(tp + 12);
      float a0 = 0.f, a1 = 0.f, a2 = 0.f, a3 = 0.f;
      a0 = fmaf(readlane_f(wgt, wb16 + 0),  e0.x, a0);
      a1 = fmaf(readlane_f(wgt, wb16 + 1),  e0.y, a1);
      a2 = fmaf(readlane_f(wgt, wb16 + 2),  e0.z, a2);
      a3 = fmaf(readlane_f(wgt, wb16 + 3),  e0.w, a3);
      a0 = fmaf(readlane_f(wgt, wb16 + 4),  e1.x, a0);
      a1 = fmaf(readlane_f(wgt, wb16 + 5),  e1.y, a1);
      a2 = fmaf(readlane_f(wgt, wb16 + 6),  e1.z, a2);
      a3 = fmaf(readlane_f(wgt, wb16 + 7),  e1.w, a3);
      a0 = fmaf(readlane_f(wgt, wb16 + 8),  e2.x, a0);
      a1 = fmaf(readlane_f(wgt, wb16 + 9),  e2.y, a1);
      a2 = fmaf(readlane_f(wgt, wb16 + 10), e2.z, a2);
      a3 = fmaf(readlane_f(wgt, wb16 + 11), e2.w, a3);
      a0 = fmaf(readlane_f(wgt, wb16 + 12), e3.x, a0);
      a1 = fmaf(readlane_f(wgt, wb16 + 13), e3.y, a1);
      a2 = fmaf(readlane_f(wgt, wb16 + 14), e3.z, a2);
      a3 = fmaf(readlane_f(wgt, wb16 + 15), e3.w, a3);
      fpart[s & 1][w][lane] = (a0 + a1) + (a2 + a3);
      mprev = mLDS[TT - 1 - s];
      if (s <= TT - 3) slxc = slx[((TT - 2 - s) * BB + b) * SS + lane];
      pts = ts; ts = (ts == 2) ? 0 : ts + 1;
      BARRIER();
    }
    {
      const int fs = (TT - 2) & 1;
      float eh = (fpart[fs][0][lane] + fpart[fs][1][lane])
               + (fpart[fs][2][lane] + fpart[fs][3][lane]);
      float rsv = ((rsp[pts][0][lane] + rsp[pts][1][lane]) + (rsp[pts][2][lane] + rsp[pts][3][lane]))
                + ((rsp[pts][4][lane] + rsp[pts][5][lane]) + (rsp[pts][6][lane] + rsp[pts][7][lane]));
      float v = __logf(fmaf(eh * __builtin_amdgcn_rcpf(rsv), rWc, EPSF));
      breg = (mprev == 1.0f) ? v : 0.0f;
      if (w == 0) log_beta[b * SS + lane] = breg;
    }
  }
}

// --- q_z = softmax(log(alpha+EPS) + log_beta)
__global__ __launch_bounds__(256) void qz_kernel(
    const float* __restrict__ alpha, const float* __restrict__ log_beta,
    float* __restrict__ out){
  const int lane = threadIdx.x & 63;
  const int w = threadIdx.x >> 6;
  const int row = blockIdx.x * 4 + w;
  float v = __logf(alpha[row * SS + lane] + EPSF) + log_beta[row * SS + lane];
  float mx = wave_max(v);
  float e = __expf(v - mx);
  float sm = wave_sum(e);
  out[row * SS + lane] = e * __builtin_amdgcn_rcpf(sm);
}

extern "C" void kernel_launch(void* const* d_in, const int* in_sizes, int n_in,
                              void* d_out, int out_size, void* d_ws, size_t ws_size,
                              hipStream_t stream){
  const float* x      = (const float*)d_in[0];
  const float* a      = (const float*)d_in[1];
  const float* mask   = (const float*)d_in[2];
  const float* mu     = (const float*)d_in[3];
  const float* logv   = (const float*)d_in[4];
  const float* il     = (const float*)d_in[5];
  const float* w_base = (const float*)d_in[6];
  const float* w_act  = (const float*)d_in[7];
  float* out = (float*)d_out;

  float* ws = (float*)d_ws;
  const size_t TBS = (size_t)TT * BB * SS;
  float* iv       = ws;                   // 2048 (+cs, pad to 4096)
  float* cs       = ws + 2048;
  float* slx      = ws + 4096;
  float* alpha    = slx + TBS;
  float* log_beta = alpha + TBS;
  float* fwd_u    = log_beta + TBS;       // 2048
  float* bwd_b    = fwd_u + 2048;         // 2048 (pad to 8192)
  const size_t base = 4096 + 3 * TBS + 8192;   // floats
  f16* ET = (f16*)(ws + base);

  // W=128 keeps the window tile set (67 MB) LLC-resident between produce & scan
  int W = 0;
  const int tiers[3] = {128, 64, 32};
  for (int i = 0; i < 3; ++i){
    const size_t need = base * 4 + 2 * (size_t)tiers[i] * BB * 4096 * 2;
    if (need <= ws_size){ W = tiers[i]; break; }
  }

  prep_kernel<<<8, 256, 0, stream>>>(logv, iv, cs);
  logpx_kernel<<<TT * BB / 4, 256, 0, stream>>>(x, mu, iv, cs, slx);
  if (W > 0){
    f16* E = ET + (size_t)W * BB * 4096;
    const int nw = (TT - 1 + W - 1) / W;
    for (int k = 0; k < nw; ++k){
      const int f_lo = k * W;
      const int f_cnt = ((TT - 1) - f_lo < W) ? ((TT - 1) - f_lo) : W;
      const int b_hi = (TT - 1) - k * W;
      const int b_lo = (b_hi - W > 0) ? (b_hi - W) : 0;
      const int b_cnt = b_hi - b_lo;
      produce_kernel<<<(f_cnt + b_cnt) * 8, 256, 0, stream>>>(
          a, w_base, w_act, ET, E, f_lo, f_cnt, b_lo, b_cnt);
      scan_win_kernel<<<2 * BB, 64, 0, stream>>>(
          slx, mask, il, ET, E, alpha, log_beta, fwd_u, bwd_b,
          f_lo, f_cnt, b_lo, b_cnt);
    }
  } else {
    scan_kernel<<<2 * BB, 768, 0, stream>>>(slx, mask, il, a, w_base, w_act,
                                            alpha, log_beta);
  }
  qz_kernel<<<TT * BB / 4, 256, 0, stream>>>(alpha, log_beta, out);
}

// Round 9
// 565.084 us; speedup vs baseline: 1.6658x; 1.2290x over previous
//
#include <hip/hip_runtime.h>
#include <math.h>

#define TT 512
#define BB 32
#define SS 64
#define AA 8
#define DD 32
#define EPSF 1e-6f
#define SEPS (64.0f * 1e-6f)   // reference adds EPS under the 64-term i-sum
#define TS 68                  // (fallback kernel) tile row stride

typedef _Float16 f16;
typedef f16 h8 __attribute__((ext_vector_type(8)));   // 16 B = 8 halves

__device__ __forceinline__ int   f2i(float x){ return __float_as_int(x); }
__device__ __forceinline__ float i2f(int x){ return __int_as_float(x); }
__device__ __forceinline__ float readlane_f(float v, int l){
  return i2f(__builtin_amdgcn_readlane(f2i(v), l));
}
template<int CTRL, int RMASK>
__device__ __forceinline__ float dpp_add(float x){
  return x + i2f(__builtin_amdgcn_update_dpp(0, f2i(x), CTRL, RMASK, 0xf, true));
}
__device__ __forceinline__ float wave_sum_dpp(float x){
  x = dpp_add<0x111, 0xf>(x);
  x = dpp_add<0x112, 0xf>(x);
  x = dpp_add<0x114, 0xf>(x);
  x = dpp_add<0x118, 0xf>(x);
  x = dpp_add<0x142, 0xa>(x);
  x = dpp_add<0x143, 0xc>(x);
  return readlane_f(x, 63);
}
__device__ __forceinline__ float wave_sum(float v){
  #pragma unroll
  for (int m = 1; m < 64; m <<= 1) v += __shfl_xor(v, m, 64);
  return v;
}
__device__ __forceinline__ float wave_max(float v){
  #pragma unroll
  for (int m = 1; m < 64; m <<= 1) v = fmaxf(v, __shfl_xor(v, m, 64));
  return v;
}
#define BARRIER() asm volatile("s_waitcnt lgkmcnt(0)\n\ts_barrier" ::: "memory")
// IR-level fence: loads issued above cannot sink below (asm may write memory)
#define LFENCE() asm volatile("" ::: "memory")

// --- kernel 0
__global__ void prep_kernel(const float* __restrict__ logv,
                            float* __restrict__ iv, float* __restrict__ cs){
  int gid = blockIdx.x * blockDim.x + threadIdx.x;
  if (gid < SS * DD) iv[gid] = __expf(-logv[gid]);
  if (gid < SS){
    float s = 0.f;
    #pragma unroll
    for (int d = 0; d < DD; ++d) s += logv[gid * DD + d];
    cs[gid] = s + (float)DD * 1.8378770664093453f;
  }
}

// --- kernel 1: slx = lx - rowmax
__global__ __launch_bounds__(256) void logpx_kernel(
    const float* __restrict__ x, const float* __restrict__ mu,
    const float* __restrict__ iv, const float* __restrict__ cs,
    float* __restrict__ slx_out){
  const int lane = threadIdx.x & 63;
  const int w = threadIdx.x >> 6;
  const int row = blockIdx.x * 4 + w;
  const float* __restrict__ xp  = x  + row * DD;
  const float* __restrict__ mup = mu + lane * DD;
  const float* __restrict__ ivp = iv + lane * DD;
  float acc = 0.f;
  #pragma unroll
  for (int d = 0; d < DD; ++d){
    float diff = xp[d] - mup[d];
    acc = fmaf(diff * diff, ivp[d], acc);
  }
  float lx = -0.5f * (acc + cs[lane]);
  float mx = wave_max(lx);
  slx_out[row * SS + lane] = lx - mx;
}

// --- produce: normalized fp16 tiles; block = one t x 16 batches (weight loads
// amortized 16x). fwd: ET[j][i] via LDS transpose; bwd: E[i][j] direct.
// grid = (f_cnt + b_cnt) * 2 blocks, 256 threads.
__global__ __launch_bounds__(256) void produce_kernel(
    const float* __restrict__ a, const float* __restrict__ w_base,
    const float* __restrict__ w_act, f16* __restrict__ ET,
    f16* __restrict__ E, int f_lo, int f_cnt, int b_lo, int b_cnt){
  const int lane = threadIdx.x & 63;   // row i
  const int wv = threadIdx.x >> 6;
  const int jb = wv * 16;
  int blk = blockIdx.x;
  const bool isF = blk < f_cnt * 2;
  if (!isF) blk -= f_cnt * 2;
  const int rel = blk >> 1;
  const int bh = (blk & 1) * 16;
  const int t = (isF ? f_lo : b_lo) + rel;

  float4 wb4[4], wa4[8][4];
  {
    const float4* wbp = (const float4*)(w_base + lane * SS + jb);
    #pragma unroll
    for (int q = 0; q < 4; ++q) wb4[q] = wbp[q];
    #pragma unroll
    for (int k = 0; k < 8; ++k){
      const float4* wap = (const float4*)(w_act + ((k * SS + lane) * SS) + jb);
      #pragma unroll
      for (int q = 0; q < 4; ++q) wa4[k][q] = wap[q];
    }
  }
  __shared__ float part[4][SS];
  __shared__ f16 tr[SS][SS + 8];
  for (int g = 0; g < 16; ++g){
    const int b = bh + g;
    float aa[8];
    const float* __restrict__ ap = a + (t * BB + b) * AA;
    #pragma unroll
    for (int k = 0; k < 8; ++k) aa[k] = ap[k];
    float4 uv[4];
    #pragma unroll
    for (int q = 0; q < 4; ++q){
      uv[q] = wb4[q];
      #pragma unroll
      for (int k = 0; k < 8; ++k){
        uv[q].x = fmaf(aa[k], wa4[k][q].x, uv[q].x);
        uv[q].y = fmaf(aa[k], wa4[k][q].y, uv[q].y);
        uv[q].z = fmaf(aa[k], wa4[k][q].z, uv[q].z);
        uv[q].w = fmaf(aa[k], wa4[k][q].w, uv[q].w);
      }
    }
    float ev[16]; float rpart = 0.f;
    #pragma unroll
    for (int q = 0; q < 4; ++q){
      ev[4*q+0] = __expf(uv[q].x); ev[4*q+1] = __expf(uv[q].y);
      ev[4*q+2] = __expf(uv[q].z); ev[4*q+3] = __expf(uv[q].w);
      rpart += ev[4*q+0] + ev[4*q+1] + ev[4*q+2] + ev[4*q+3];
    }
    part[wv][lane] = rpart;
    __syncthreads();                                  // sync1: partials
    float rs = part[0][lane] + part[1][lane] + part[2][lane] + part[3][lane];
    float rn = __builtin_amdgcn_rcpf(rs);
    const size_t tb = (size_t)(rel * BB + b) << 12;   // 4096 halves per tile
    if (isF){
      #pragma unroll
      for (int c = 0; c < 16; ++c) tr[jb + c][lane] = (f16)(ev[c] * rn);
      __syncthreads();                                // sync2: transpose staged
      const int j = threadIdx.x >> 2, seg = threadIdx.x & 3;
      h8 v0 = *(const h8*)&tr[j][seg * 16];
      h8 v1 = *(const h8*)&tr[j][seg * 16 + 8];
      f16* __restrict__ dst = ET + tb + j * SS + seg * 16;
      *(h8*)dst = v0; *(h8*)(dst + 8) = v1;           // coalesced 32 B/thread
    } else {
      f16* __restrict__ dst = E + tb + lane * SS + jb;
      h8 o0, o1;
      #pragma unroll
      for (int k = 0; k < 8; ++k){ o0[k] = (f16)(ev[k] * rn); o1[k] = (f16)(ev[8+k] * rn); }
      *(h8*)(dst) = o0; *(h8*)(dst + 8) = o1;
    }
  }
}

// matvec helper: by-value h8 keeps everything in VGPRs; base is compile-time.
__device__ __forceinline__ void mv8(float& x0, float& x1, float& x2, float& x3,
                                    float src, h8 bv, int base){
  x0 = fmaf(readlane_f(src, base + 0), (float)bv[0], x0);
  x1 = fmaf(readlane_f(src, base + 1), (float)bv[1], x1);
  x2 = fmaf(readlane_f(src, base + 2), (float)bv[2], x2);
  x3 = fmaf(readlane_f(src, base + 3), (float)bv[3], x3);
  x0 = fmaf(readlane_f(src, base + 4), (float)bv[4], x0);
  x1 = fmaf(readlane_f(src, base + 5), (float)bv[5], x1);
  x2 = fmaf(readlane_f(src, base + 6), (float)bv[6], x2);
  x3 = fmaf(readlane_f(src, base + 7), (float)bv[7], x3);
}

#define DECLB(N) h8 N##0, N##1, N##2, N##3, N##4, N##5, N##6, N##7;
// LFENCE pins the 8 loads at their program point (cannot sink to use site)
#define LDB(TB, N, rr) { const h8* __restrict__ _p = (TB) + (size_t)(rr) * (BB * 512); \
  N##0=_p[0]; N##1=_p[1]; N##2=_p[2]; N##3=_p[3]; N##4=_p[4]; N##5=_p[5]; N##6=_p[6]; N##7=_p[7]; \
  LFENCE(); }
#define MATVEC(N, SRC, P0, P1, P2, P3) \
  mv8(P0,P1,P2,P3,SRC,N##0,0);  mv8(P0,P1,P2,P3,SRC,N##1,8); \
  mv8(P0,P1,P2,P3,SRC,N##2,16); mv8(P0,P1,P2,P3,SRC,N##3,24); \
  mv8(P0,P1,P2,P3,SRC,N##4,32); mv8(P0,P1,P2,P3,SRC,N##5,40); \
  mv8(P0,P1,P2,P3,SRC,N##6,48); mv8(P0,P1,P2,P3,SRC,N##7,56);

// --- scan over one window: 64 blocks x 64 threads, register ring depth-3.
__global__ __launch_bounds__(64, 1) void scan_win_kernel(
    const float* __restrict__ slx, const float* __restrict__ mask,
    const float* __restrict__ il,
    const f16* __restrict__ ET, const f16* __restrict__ E,
    float* __restrict__ alpha, float* __restrict__ log_beta,
    float* __restrict__ fwd_u, float* __restrict__ bwd_b,
    int f_lo, int f_cnt, int b_lo, int b_cnt){
  const int lane = threadIdx.x;
  if (blockIdx.x < BB){
    // ---------------- FORWARD (lane = j; ET[j][i]) ----------------
    const int b = blockIdx.x;
    const h8* __restrict__ TBF = (const h8*)ET + ((size_t)b << 9) + lane * 8;
    float u, c;
    if (f_lo == 0){
      u = __expf(slx[b * SS + lane] + il[lane]);
      c = __builtin_amdgcn_rcpf(wave_sum_dpp(u));
      alpha[b * SS + lane] = u * c;
    } else {
      u = fwd_u[b * SS + lane];
      c = __builtin_amdgcn_rcpf(wave_sum_dpp(u));
    }
    const float* __restrict__ sb = slx + b * SS + lane;
    float* __restrict__ ab = alpha + b * SS + lane;
    float slc = sb[(f_lo + 1) * (BB * SS)];
    float sl1 = sb[((f_lo + 2 <= TT - 1) ? (f_lo + 2) : (TT - 1)) * (BB * SS)];
    float sl2 = sb[((f_lo + 3 <= TT - 1) ? (f_lo + 3) : (TT - 1)) * (BB * SS)];
    DECLB(A) DECLB(B) DECLB(C) DECLB(D)
#define FCL(x) (((x) < f_cnt) ? (x) : (f_cnt - 1))
#define FSTEP(N, rr) { \
      float p0=0.f,p1=0.f,p2=0.f,p3=0.f; \
      MATVEC(N, u, p0, p1, p2, p3) \
      float S = (p0 + p1) + (p2 + p3); \
      float un = __expf(slc) * fmaf(c, S, SEPS); \
      c = __builtin_amdgcn_rcpf(wave_sum_dpp(un)); \
      u = un; \
      ab[(f_lo + 1 + (rr)) * (BB * SS)] = un * c; \
      slc = sl1; sl1 = sl2; \
      { int tn = f_lo + 4 + (rr); if (tn > TT - 1) tn = TT - 1; \
        sl2 = sb[tn * (BB * SS)]; } }
    LDB(TBF, A, 0);
    LDB(TBF, B, FCL(1));
    LDB(TBF, C, FCL(2));
    int r = 0;
    for (;;){
      LDB(TBF, D, FCL(r + 3)); FSTEP(A, r); if (++r >= f_cnt) break;
      LDB(TBF, A, FCL(r + 3)); FSTEP(B, r); if (++r >= f_cnt) break;
      LDB(TBF, B, FCL(r + 3)); FSTEP(C, r); if (++r >= f_cnt) break;
      LDB(TBF, C, FCL(r + 3)); FSTEP(D, r); if (++r >= f_cnt) break;
    }
#undef FSTEP
#undef FCL
    fwd_u[b * SS + lane] = u;
  } else {
    // ---------------- BACKWARD (lane = i; E[i][j]) ----------------
    const int bb = blockIdx.x - BB;
    const h8* __restrict__ TBB = (const h8*)E + ((size_t)bb << 9) + lane * 8;
    float breg;
    if (b_lo + b_cnt == TT - 1){
      breg = 0.f;
      log_beta[(TT - 1) * (BB * SS) + bb * SS + lane] = 0.f;
    } else {
      breg = bwd_b[bb * SS + lane];
    }
    const float* __restrict__ sb = slx + bb * SS + lane;
    const float* __restrict__ mb = mask + bb;
    float* __restrict__ lb = log_beta + bb * SS + lane;
    const int r0 = b_cnt - 1;
    float slc = sb[(b_lo + r0 + 1) * (BB * SS)];
    float sl1 = sb[(b_lo + ((r0 - 1 > 0) ? r0 - 1 : 0) + 1) * (BB * SS)];
    float sl2 = sb[(b_lo + ((r0 - 2 > 0) ? r0 - 2 : 0) + 1) * (BB * SS)];
    float mc = mb[(b_lo + r0 + 1) * BB];
    float m1 = mb[(b_lo + ((r0 - 1 > 0) ? r0 - 1 : 0) + 1) * BB];
    float m2 = mb[(b_lo + ((r0 - 2 > 0) ? r0 - 2 : 0) + 1) * BB];
    DECLB(A) DECLB(B) DECLB(C) DECLB(D)
#define BCL(x) (((x) > 0) ? (x) : 0)
#define BSTEP(N, rr) { \
      float wgt = __expf(slc + breg); \
      float W = wave_sum_dpp(wgt); \
      float rW = __builtin_amdgcn_rcpf(W); \
      float p0=0.f,p1=0.f,p2=0.f,p3=0.f; \
      MATVEC(N, wgt, p0, p1, p2, p3) \
      float dot = (p0 + p1) + (p2 + p3); \
      float v = __logf(fmaf(dot, rW, EPSF)); \
      breg = (mc == 1.0f) ? v : 0.0f; \
      lb[(b_lo + (rr)) * (BB * SS)] = breg; \
      slc = sl1; sl1 = sl2; mc = m1; m1 = m2; \
      { int rn2 = (rr) - 3; if (rn2 < 0) rn2 = 0; \
        sl2 = sb[(b_lo + rn2 + 1) * (BB * SS)]; \
        m2  = mb[(b_lo + rn2 + 1) * BB]; } }
    LDB(TBB, A, r0);
    LDB(TBB, B, BCL(r0 - 1));
    LDB(TBB, C, BCL(r0 - 2));
    int r = r0;
    for (;;){
      LDB(TBB, D, BCL(r - 3)); BSTEP(A, r); if (--r < 0) break;
      LDB(TBB, A, BCL(r - 3)); BSTEP(B, r); if (--r < 0) break;
      LDB(TBB, B, BCL(r - 3)); BSTEP(C, r); if (--r < 0) break;
      LDB(TBB, C, BCL(r - 3)); BSTEP(D, r); if (--r < 0) break;
    }
#undef BSTEP
#undef BCL
    bwd_b[bb * SS + lane] = breg;
  }
}

// ================== R5 fallback scan (proven 402 us, 12.6 MB ws) ==================
__global__ __launch_bounds__(768) void scan_kernel(
    const float* __restrict__ slx, const float* __restrict__ mask,
    const float* __restrict__ il, const float* __restrict__ a,
    const float* __restrict__ w_base, const float* __restrict__ w_act,
    float* __restrict__ alpha, float* __restrict__ log_beta){
  const int lane = threadIdx.x & 63;
  const int w    = threadIdx.x >> 6;
  const bool is_fwd = (blockIdx.x < BB);
  const int b = is_fwd ? blockIdx.x : (blockIdx.x - BB);
  __shared__ __align__(16) float tile[3][SS * TS];
  __shared__ float rsp[3][8][SS];
  __shared__ float fpart[2][4][SS];
  __shared__ __align__(16) float aLDS[TT * AA];
  __shared__ float mLDS[TT];
  for (int idx = threadIdx.x; idx < TT * AA; idx += 768){
    int t = idx >> 3, k = idx & 7;
    aLDS[idx] = a[(t * BB + b) * AA + k];
  }
  for (int idx = threadIdx.x; idx < TT; idx += 768)
    mLDS[idx] = mask[idx * BB + b];
  if (w >= 4){
    const int pw = w - 4;
    const int jb = pw * 8;
    float wb[8], wa[8][8];
    #pragma unroll
    for (int jj = 0; jj < 8; ++jj){
      wb[jj] = w_base[lane * SS + jb + jj];
      #pragma unroll
      for (int k = 0; k < 8; ++k)
        wa[k][jj] = w_act[(k * SS + lane) * SS + jb + jj];
    }
    float aa[8], aan[8];
    {
      const int t0 = is_fwd ? 0 : (TT - 2);
      const float* __restrict__ ap = a + (t0 * BB + b) * AA;
      #pragma unroll
      for (int k = 0; k < 8; ++k) aa[k] = ap[k];
      const int t1 = is_fwd ? 1 : (TT - 3);
      const float* __restrict__ ap1 = a + (t1 * BB + b) * AA;
      #pragma unroll
      for (int k = 0; k < 8; ++k) aan[k] = ap1[k];
    }
    {
      float ev[8]; float racc = 0.f;
      #pragma unroll
      for (int jj = 0; jj < 8; ++jj){
        float u = wb[jj];
        #pragma unroll
        for (int k = 0; k < 8; ++k) u = fmaf(aa[k], wa[k][jj], u);
        ev[jj] = __expf(u); racc += ev[jj];
      }
      *(float4*)&tile[0][lane * TS + jb]     = make_float4(ev[0],ev[1],ev[2],ev[3]);
      *(float4*)&tile[0][lane * TS + jb + 4] = make_float4(ev[4],ev[5],ev[6],ev[7]);
      rsp[0][pw][lane] = racc;
    }
    BARRIER();
    int tw = 1;
    for (int s = 0; s < TT - 1; ++s){
      if (s <= TT - 3){
        #pragma unroll
        for (int k = 0; k < 8; ++k) aa[k] = aan[k];
        if (s + 1 <= TT - 3){
          const int tn = is_fwd ? (s + 2) : (TT - 4 - s);
          #pragma unroll
          for (int k = 0; k < 8; ++k) aan[k] = aLDS[tn * AA + k];
        }
        float ev[8]; float racc = 0.f;
        #pragma unroll
        for (int jj = 0; jj < 8; ++jj){
          float u = wb[jj];
          #pragma unroll
          for (int k = 0; k < 8; ++k) u = fmaf(aa[k], wa[k][jj], u);
          ev[jj] = __expf(u); racc += ev[jj];
        }
        *(float4*)&tile[tw][lane * TS + jb]     = make_float4(ev[0],ev[1],ev[2],ev[3]);
        *(float4*)&tile[tw][lane * TS + jb + 4] = make_float4(ev[4],ev[5],ev[6],ev[7]);
        rsp[tw][pw][lane] = racc;
        tw = (tw == 2) ? 0 : tw + 1;
      }
      BARRIER();
    }
  } else if (is_fwd){
    const int wb16 = __builtin_amdgcn_readfirstlane(w * 16);
    float u = __expf(slx[b * SS + lane] + il[lane]);
    float c = __builtin_amdgcn_rcpf(wave_sum_dpp(u));
    if (w == 0) alpha[b * SS + lane] = u * c;
    float slxn = slx[(BB + b) * SS + lane];
    float elxc = 0.f;
    BARRIER();
    int ts = 0;
    for (int s = 0; s < TT - 1; ++s){
      if (s > 0){
        const int fs = (s - 1) & 1;
        float S = (fpart[fs][0][lane] + fpart[fs][1][lane])
                + (fpart[fs][2][lane] + fpart[fs][3][lane]);
        u = elxc * fmaf(c, S, SEPS);
        c = __builtin_amdgcn_rcpf(wave_sum_dpp(u));
        if (w == 0) alpha[(s * BB + b) * SS + lane] = u * c;
      }
      float rs = ((rsp[ts][0][lane] + rsp[ts][1][lane]) + (rsp[ts][2][lane] + rsp[ts][3][lane]))
               + ((rsp[ts][4][lane] + rsp[ts][5][lane]) + (rsp[ts][6][lane] + rsp[ts][7][lane]));
      float va = u * __builtin_amdgcn_rcpf(rs);
      const float* __restrict__ tp = &tile[ts][0];
      float a0 = 0.f, a1 = 0.f, a2 = 0.f, a3 = 0.f;
      #pragma unroll
      for (int r = 0; r < 16; r += 4){
        a0 = fmaf(readlane_f(va, wb16 + r    ), tp[(wb16 + r    ) * TS + lane], a0);
        a1 = fmaf(readlane_f(va, wb16 + r + 1), tp[(wb16 + r + 1) * TS + lane], a1);
        a2 = fmaf(readlane_f(va, wb16 + r + 2), tp[(wb16 + r + 2) * TS + lane], a2);
        a3 = fmaf(readlane_f(va, wb16 + r + 3), tp[(wb16 + r + 3) * TS + lane], a3);
      }
      fpart[s & 1][w][lane] = (a0 + a1) + (a2 + a3);
      elxc = __expf(slxn);
      if (s + 2 <= TT - 1) slxn = slx[((s + 2) * BB + b) * SS + lane];
      ts = (ts == 2) ? 0 : ts + 1;
      BARRIER();
    }
    {
      const int fs = (TT - 2) & 1;
      float S = (fpart[fs][0][lane] + fpart[fs][1][lane])
              + (fpart[fs][2][lane] + fpart[fs][3][lane]);
      u = elxc * fmaf(c, S, SEPS);
      c = __builtin_amdgcn_rcpf(wave_sum_dpp(u));
      if (w == 0) alpha[((TT - 1) * BB + b) * SS + lane] = u * c;
    }
  } else {
    const int wb16 = __builtin_amdgcn_readfirstlane(w * 16);
    float breg = 0.f, rWc = 1.f;
    if (w == 0) log_beta[((TT - 1) * BB + b) * SS + lane] = 0.f;
    float slxc = slx[((TT - 1) * BB + b) * SS + lane];
    float mprev = 1.f;
    BARRIER();
    int ts = 0, pts = 2;
    for (int s = 0; s < TT - 1; ++s){
      if (s > 0){
        const int fs = (s - 1) & 1;
        float eh = (fpart[fs][0][lane] + fpart[fs][1][lane])
                 + (fpart[fs][2][lane] + fpart[fs][3][lane]);
        float rsv = ((rsp[pts][0][lane] + rsp[pts][1][lane]) + (rsp[pts][2][lane] + rsp[pts][3][lane]))
                  + ((rsp[pts][4][lane] + rsp[pts][5][lane]) + (rsp[pts][6][lane] + rsp[pts][7][lane]));
        float v = __logf(fmaf(eh * __builtin_amdgcn_rcpf(rsv), rWc, EPSF));
        breg = (mprev == 1.0f) ? v : 0.0f;
        if (w == 0) log_beta[((TT - 1 - s) * BB + b) * SS + lane] = breg;
      }
      float wgt = __expf(slxc + breg);
      float W = wave_sum_dpp(wgt);
      rWc = __builtin_amdgcn_rcpf(W);
      const float* __restrict__ tp = &tile[ts][lane * TS + wb16];
      float4 e0 = *(const float4*)(tp);
      float4 e1 = *(const float4*)(tp + 4);
      float4 e2 = *(const float4*)(tp + 8);
      float4 e3 = *(const float4*)(tp + 12);
      float a0 = 0.f, a1 = 0.f, a2 = 0.f, a3 = 0.f;
      a0 = fmaf(readlane_f(wgt, wb16 + 0),  e0.x, a0);
      a1 = fmaf(readlane_f(wgt, wb16 + 1),  e0.y, a1);
      a2 = fmaf(readlane_f(wgt, wb16 + 2),  e0.z, a2);
      a3 = fmaf(readlane_f(wgt, wb16 + 3),  e0.w, a3);
      a0 = fmaf(readlane_f(wgt, wb16 + 4),  e1.x, a0);
      a1 = fmaf(readlane_f(wgt, wb16 + 5),  e1.y, a1);
      a2 = fmaf(readlane_f(wgt, wb16 + 6),  e1.z, a2);
      a3 = fmaf(readlane_f(wgt, wb16 + 7),  e1.w, a3);
      a0 = fmaf(readlane_f(wgt, wb16 + 8),  e2.x, a0);
      a1 = fmaf(readlane_f(wgt, wb16 + 9),  e2.y, a1);
      a2 = fmaf(readlane_f(wgt, wb16 + 10), e2.z, a2);
      a3 = fmaf(readlane_f(wgt, wb16 + 11), e2.w, a3);
      a0 = fmaf(readlane_f(wgt, wb16 + 12), e3.x, a0);
      a1 = fmaf(readlane_f(wgt, wb16 + 13), e3.y, a1);
      a2 = fmaf(readlane_f(wgt, wb16 + 14), e3.z, a2);
      a3 = fmaf(readlane_f(wgt, wb16 + 15), e3.w, a3);
      fpart[s & 1][w][lane] = (a0 + a1) + (a2 + a3);
      mprev = mLDS[TT - 1 - s];
      if (s <= TT - 3) slxc = slx[((TT - 2 - s) * BB + b) * SS + lane];
      pts = ts; ts = (ts == 2) ? 0 : ts + 1;
      BARRIER();
    }
    {
      const int fs = (TT - 2) & 1;
      float eh = (fpart[fs][0][lane] + fpart[fs][1][lane])
               + (fpart[fs][2][lane] + fpart[fs][3][lane]);
      float rsv = ((rsp[pts][0][lane] + rsp[pts][1][lane]) + (rsp[pts][2][lane] + rsp[pts][3][lane]))
                + ((rsp[pts][4][lane] + rsp[pts][5][lane]) + (rsp[pts][6][lane] + rsp[pts][7][lane]));
      float v = __logf(fmaf(eh * __builtin_amdgcn_rcpf(rsv), rWc, EPSF));
      breg = (mprev == 1.0f) ? v : 0.0f;
      if (w == 0) log_beta[b * SS + lane] = breg;
    }
  }
}

// --- q_z = softmax(log(alpha+EPS) + log_beta)
__global__ __launch_bounds__(256) void qz_kernel(
    const float* __restrict__ alpha, const float* __restrict__ log_beta,
    float* __restrict__ out){
  const int lane = threadIdx.x & 63;
  const int w = threadIdx.x >> 6;
  const int row = blockIdx.x * 4 + w;
  float v = __logf(alpha[row * SS + lane] + EPSF) + log_beta[row * SS + lane];
  float mx = wave_max(v);
  float e = __expf(v - mx);
  float sm = wave_sum(e);
  out[row * SS + lane] = e * __builtin_amdgcn_rcpf(sm);
}

extern "C" void kernel_launch(void* const* d_in, const int* in_sizes, int n_in,
                              void* d_out, int out_size, void* d_ws, size_t ws_size,
                              hipStream_t stream){
  const float* x      = (const float*)d_in[0];
  const float* a      = (const float*)d_in[1];
  const float* mask   = (const float*)d_in[2];
  const float* mu     = (const float*)d_in[3];
  const float* logv   = (const float*)d_in[4];
  const float* il     = (const float*)d_in[5];
  const float* w_base = (const float*)d_in[6];
  const float* w_act  = (const float*)d_in[7];
  float* out = (float*)d_out;

  float* ws = (float*)d_ws;
  const size_t TBS = (size_t)TT * BB * SS;
  float* iv       = ws;                   // 2048 (+cs, pad to 4096)
  float* cs       = ws + 2048;
  float* slx      = ws + 4096;
  float* alpha    = slx + TBS;
  float* log_beta = alpha + TBS;
  float* fwd_u    = log_beta + TBS;       // 2048
  float* bwd_b    = fwd_u + 2048;         // 2048 (pad to 8192)
  const size_t base = 4096 + 3 * TBS + 8192;   // floats
  f16* ET = (f16*)(ws + base);

  // W=128 keeps the window tile set (67 MB) LLC-resident between produce & scan
  int W = 0;
  const int tiers[3] = {128, 64, 32};
  for (int i = 0; i < 3; ++i){
    const size_t need = base * 4 + 2 * (size_t)tiers[i] * BB * 4096 * 2;
    if (need <= ws_size){ W = tiers[i]; break; }
  }

  prep_kernel<<<8, 256, 0, stream>>>(logv, iv, cs);
  logpx_kernel<<<TT * BB / 4, 256, 0, stream>>>(x, mu, iv, cs, slx);
  if (W > 0){
    f16* E = ET + (size_t)W * BB * 4096;
    const int nw = (TT - 1 + W - 1) / W;
    for (int k = 0; k < nw; ++k){
      const int f_lo = k * W;
      const int f_cnt = ((TT - 1) - f_lo < W) ? ((TT - 1) - f_lo) : W;
      const int b_hi = (TT - 1) - k * W;
      const int b_lo = (b_hi - W > 0) ? (b_hi - W) : 0;
      const int b_cnt = b_hi - b_lo;
      produce_kernel<<<(f_cnt + b_cnt) * 2, 256, 0, stream>>>(
          a, w_base, w_act, ET, E, f_lo, f_cnt, b_lo, b_cnt);
      scan_win_kernel<<<2 * BB, 64, 0, stream>>>(
          slx, mask, il, ET, E, alpha, log_beta, fwd_u, bwd_b,
          f_lo, f_cnt, b_lo, b_cnt);
    }
  } else {
    scan_kernel<<<2 * BB, 768, 0, stream>>>(slx, mask, il, a, w_base, w_act,
                                            alpha, log_beta);
  }
  qz_kernel<<<TT * BB / 4, 256, 0, stream>>>(alpha, log_beta, out);
}

// Round 10
// 504.009 us; speedup vs baseline: 1.8677x; 1.1212x over previous
//
#include <hip/hip_runtime.h>
#include <math.h>

#define TT 512
#define BB 32
#define SS 64
#define AA 8
#define DD 32
#define EPSF 1e-6f
#define SEPS (64.0f * 1e-6f)   // reference adds EPS under the 64-term i-sum
#define TS 68                  // (fallback kernel) tile row stride
#define LSTR 96                // LDS tile row stride in halves (192 B, 2-way banks)

typedef _Float16 f16;
typedef f16 h8 __attribute__((ext_vector_type(8)));   // 16 B = 8 halves

__device__ __forceinline__ int   f2i(float x){ return __float_as_int(x); }
__device__ __forceinline__ float i2f(int x){ return __int_as_float(x); }
__device__ __forceinline__ float readlane_f(float v, int l){
  return i2f(__builtin_amdgcn_readlane(f2i(v), l));
}
template<int CTRL, int RMASK>
__device__ __forceinline__ float dpp_add(float x){
  return x + i2f(__builtin_amdgcn_update_dpp(0, f2i(x), CTRL, RMASK, 0xf, true));
}
__device__ __forceinline__ float wave_sum_dpp(float x){
  x = dpp_add<0x111, 0xf>(x);
  x = dpp_add<0x112, 0xf>(x);
  x = dpp_add<0x114, 0xf>(x);
  x = dpp_add<0x118, 0xf>(x);
  x = dpp_add<0x142, 0xa>(x);
  x = dpp_add<0x143, 0xc>(x);
  return readlane_f(x, 63);
}
__device__ __forceinline__ float wave_sum(float v){
  #pragma unroll
  for (int m = 1; m < 64; m <<= 1) v += __shfl_xor(v, m, 64);
  return v;
}
__device__ __forceinline__ float wave_max(float v){
  #pragma unroll
  for (int m = 1; m < 64; m <<= 1) v = fmaxf(v, __shfl_xor(v, m, 64));
  return v;
}
// raw barrier: drains LDS only; global loads stay in flight (no vmcnt drain)
#define BARRIER() asm volatile("s_waitcnt lgkmcnt(0)\n\ts_barrier" ::: "memory")

// --- kernel 0
__global__ void prep_kernel(const float* __restrict__ logv,
                            float* __restrict__ iv, float* __restrict__ cs){
  int gid = blockIdx.x * blockDim.x + threadIdx.x;
  if (gid < SS * DD) iv[gid] = __expf(-logv[gid]);
  if (gid < SS){
    float s = 0.f;
    #pragma unroll
    for (int d = 0; d < DD; ++d) s += logv[gid * DD + d];
    cs[gid] = s + (float)DD * 1.8378770664093453f;
  }
}

// --- kernel 1: slx = lx - rowmax
__global__ __launch_bounds__(256) void logpx_kernel(
    const float* __restrict__ x, const float* __restrict__ mu,
    const float* __restrict__ iv, const float* __restrict__ cs,
    float* __restrict__ slx_out){
  const int lane = threadIdx.x & 63;
  const int w = threadIdx.x >> 6;
  const int row = blockIdx.x * 4 + w;
  const float* __restrict__ xp  = x  + row * DD;
  const float* __restrict__ mup = mu + lane * DD;
  const float* __restrict__ ivp = iv + lane * DD;
  float acc = 0.f;
  #pragma unroll
  for (int d = 0; d < DD; ++d){
    float diff = xp[d] - mup[d];
    acc = fmaf(diff * diff, ivp[d], acc);
  }
  float lx = -0.5f * (acc + cs[lane]);
  float mx = wave_max(lx);
  slx_out[row * SS + lane] = lx - mx;
}

// --- produce (R9, proven): normalized fp16 tiles. fwd ET[j][i]; bwd E[i][j].
__global__ __launch_bounds__(256) void produce_kernel(
    const float* __restrict__ a, const float* __restrict__ w_base,
    const float* __restrict__ w_act, f16* __restrict__ ET,
    f16* __restrict__ E, int f_lo, int f_cnt, int b_lo, int b_cnt){
  const int lane = threadIdx.x & 63;   // row i
  const int wv = threadIdx.x >> 6;
  const int jb = wv * 16;
  int blk = blockIdx.x;
  const bool isF = blk < f_cnt * 2;
  if (!isF) blk -= f_cnt * 2;
  const int rel = blk >> 1;
  const int bh = (blk & 1) * 16;
  const int t = (isF ? f_lo : b_lo) + rel;

  float4 wb4[4], wa4[8][4];
  {
    const float4* wbp = (const float4*)(w_base + lane * SS + jb);
    #pragma unroll
    for (int q = 0; q < 4; ++q) wb4[q] = wbp[q];
    #pragma unroll
    for (int k = 0; k < 8; ++k){
      const float4* wap = (const float4*)(w_act + ((k * SS + lane) * SS) + jb);
      #pragma unroll
      for (int q = 0; q < 4; ++q) wa4[k][q] = wap[q];
    }
  }
  __shared__ float part[4][SS];
  __shared__ f16 tr[SS][SS + 8];
  for (int g = 0; g < 16; ++g){
    const int b = bh + g;
    float aa[8];
    const float* __restrict__ ap = a + (t * BB + b) * AA;
    #pragma unroll
    for (int k = 0; k < 8; ++k) aa[k] = ap[k];
    float4 uv[4];
    #pragma unroll
    for (int q = 0; q < 4; ++q){
      uv[q] = wb4[q];
      #pragma unroll
      for (int k = 0; k < 8; ++k){
        uv[q].x = fmaf(aa[k], wa4[k][q].x, uv[q].x);
        uv[q].y = fmaf(aa[k], wa4[k][q].y, uv[q].y);
        uv[q].z = fmaf(aa[k], wa4[k][q].z, uv[q].z);
        uv[q].w = fmaf(aa[k], wa4[k][q].w, uv[q].w);
      }
    }
    float ev[16]; float rpart = 0.f;
    #pragma unroll
    for (int q = 0; q < 4; ++q){
      ev[4*q+0] = __expf(uv[q].x); ev[4*q+1] = __expf(uv[q].y);
      ev[4*q+2] = __expf(uv[q].z); ev[4*q+3] = __expf(uv[q].w);
      rpart += ev[4*q+0] + ev[4*q+1] + ev[4*q+2] + ev[4*q+3];
    }
    part[wv][lane] = rpart;
    __syncthreads();
    float rs = part[0][lane] + part[1][lane] + part[2][lane] + part[3][lane];
    float rn = __builtin_amdgcn_rcpf(rs);
    const size_t tb = (size_t)(rel * BB + b) << 12;   // 4096 halves per tile
    if (isF){
      #pragma unroll
      for (int c = 0; c < 16; ++c) tr[jb + c][lane] = (f16)(ev[c] * rn);
      __syncthreads();
      const int j = threadIdx.x >> 2, seg = threadIdx.x & 3;
      h8 v0 = *(const h8*)&tr[j][seg * 16];
      h8 v1 = *(const h8*)&tr[j][seg * 16 + 8];
      f16* __restrict__ dst = ET + tb + j * SS + seg * 16;
      *(h8*)dst = v0; *(h8*)(dst + 8) = v1;
    } else {
      f16* __restrict__ dst = E + tb + lane * SS + jb;
      h8 o0, o1;
      #pragma unroll
      for (int k = 0; k < 8; ++k){ o0[k] = (f16)(ev[k] * rn); o1[k] = (f16)(ev[8+k] * rn); }
      *(h8*)(dst) = o0; *(h8*)(dst + 8) = o1;
    }
  }
}

// matvec helper: by-value h8, compile-time-uniform base for readlane
__device__ __forceinline__ void mv8(float& x0, float& x1, float& x2, float& x3,
                                    float src, h8 bv, int base){
  x0 = fmaf(readlane_f(src, base + 0), (float)bv[0], x0);
  x1 = fmaf(readlane_f(src, base + 1), (float)bv[1], x1);
  x2 = fmaf(readlane_f(src, base + 2), (float)bv[2], x2);
  x3 = fmaf(readlane_f(src, base + 3), (float)bv[3], x3);
  x0 = fmaf(readlane_f(src, base + 4), (float)bv[4], x0);
  x1 = fmaf(readlane_f(src, base + 5), (float)bv[5], x1);
  x2 = fmaf(readlane_f(src, base + 6), (float)bv[6], x2);
  x3 = fmaf(readlane_f(src, base + 7), (float)bv[7], x3);
}

// --- scan over one window: 64 blocks x 256 threads (4 waves per chain).
// 3-slot LDS tile ring; cooperative staging (32 B/thread) with 3-step lead;
// deferred partial combine; one raw barrier per step.
__global__ __launch_bounds__(256, 1) void scan_win_kernel(
    const float* __restrict__ slx, const float* __restrict__ mask,
    const float* __restrict__ il,
    const f16* __restrict__ ET, const f16* __restrict__ E,
    float* __restrict__ alpha, float* __restrict__ log_beta,
    float* __restrict__ fwd_u, float* __restrict__ bwd_b,
    int f_lo, int f_cnt, int b_lo, int b_cnt){
  const int tid  = threadIdx.x;
  const int lane = tid & 63;
  const int w4   = tid >> 6;
  const int w16  = __builtin_amdgcn_readfirstlane(w4 * 16);
  const int wrow = tid >> 2;             // staging: row, 4 threads/row
  const int wcol = (tid & 3) * 16;       // staging: 16-half column chunk

  __shared__ __align__(16) f16 tile[3][SS * LSTR];  // 3 x 12 KB
  __shared__ float fp[3][4][SS];                    // partials, slot-indexed

  if (blockIdx.x < BB){
    // ---------------- FORWARD (tile[j][i] = p_ij) ----------------
    const int b = blockIdx.x;
    const h8* __restrict__ GB = (const h8*)ET + (size_t)b * 512 + tid * 2;
    float u, c;
    if (f_lo == 0){
      u = __expf(slx[b * SS + lane] + il[lane]);
      c = __builtin_amdgcn_rcpf(wave_sum_dpp(u));
      if (w4 == 0) alpha[b * SS + lane] = u * c;
    } else {
      u = fwd_u[b * SS + lane];
      c = __builtin_amdgcn_rcpf(wave_sum_dpp(u));
    }
    const float* __restrict__ sb = slx + b * SS + lane;
    float* __restrict__ ab = alpha + b * SS + lane;
    float slc = sb[(f_lo + 1) * (BB * SS)];
    float sl1 = sb[((f_lo + 2 <= TT - 1) ? (f_lo + 2) : (TT - 1)) * (BB * SS)];
    float sl2 = sb[((f_lo + 3 <= TT - 1) ? (f_lo + 3) : (TT - 1)) * (BB * SS)];
    h8 Aa, Ab, Ba, Bb, Ca, Cb;
#define FLDG(NA, NB, rr) { int _tl = (rr); if (_tl > f_cnt - 1) _tl = f_cnt - 1; \
      const h8* _g = GB + (size_t)_tl * (BB * 512); NA = _g[0]; NB = _g[1]; }
    { // prologue: tile 0 -> slot 0; preload ring tiles 1..3
      h8 t0 = GB[0], t1 = GB[1];
      *(h8*)&tile[0][wrow * LSTR + wcol] = t0;
      *(h8*)&tile[0][wrow * LSTR + wcol + 8] = t1;
      FLDG(Aa, Ab, 1) FLDG(Ba, Bb, 2) FLDG(Ca, Cb, 3)
    }
    BARRIER();
#define FW_STEP(s, SL, NA, NB) { \
      if ((s) > 0) { \
        const int _ps = (SL + 2) % 3; \
        float S = (fp[_ps][0][lane] + fp[_ps][1][lane]) \
                + (fp[_ps][2][lane] + fp[_ps][3][lane]); \
        u = __expf(slc) * fmaf(c, S, SEPS); \
        c = __builtin_amdgcn_rcpf(wave_sum_dpp(u)); \
        if (w4 == 0) ab[(f_lo + (s)) * (BB * SS)] = u * c; \
        slc = sl1; sl1 = sl2; \
        int _tn = f_lo + (s) + 3; if (_tn > TT - 1) _tn = TT - 1; \
        sl2 = sb[_tn * (BB * SS)]; \
      } \
      if ((s) + 1 < f_cnt) { \
        *(h8*)&tile[(SL + 1) % 3][wrow * LSTR + wcol] = NA; \
        *(h8*)&tile[(SL + 1) % 3][wrow * LSTR + wcol + 8] = NB; \
      } \
      FLDG(NA, NB, (s) + 4) \
      { const f16* _tp = &tile[SL][lane * LSTR + w16]; \
        h8 _t0 = *(const h8*)_tp; h8 _t1 = *(const h8*)(_tp + 8); \
        float p0 = 0.f, p1 = 0.f, p2 = 0.f, p3 = 0.f; \
        mv8(p0, p1, p2, p3, u, _t0, w16); \
        mv8(p0, p1, p2, p3, u, _t1, w16 + 8); \
        fp[SL][w4][lane] = (p0 + p1) + (p2 + p3); } \
      BARRIER(); }
    int s = 0;
    for (;;){
      FW_STEP(s, 0, Aa, Ab) if (++s >= f_cnt) break;
      FW_STEP(s, 1, Ba, Bb) if (++s >= f_cnt) break;
      FW_STEP(s, 2, Ca, Cb) if (++s >= f_cnt) break;
    }
#undef FW_STEP
#undef FLDG
    { // epilogue: combine last partials -> alpha at f_lo + f_cnt
      const int ls = (f_cnt - 1) % 3;
      float S = (fp[ls][0][lane] + fp[ls][1][lane])
              + (fp[ls][2][lane] + fp[ls][3][lane]);
      u = __expf(slc) * fmaf(c, S, SEPS);
      c = __builtin_amdgcn_rcpf(wave_sum_dpp(u));
      if (w4 == 0){
        ab[(f_lo + f_cnt) * (BB * SS)] = u * c;
        fwd_u[b * SS + lane] = u;
      }
    }
  } else {
    // ---------------- BACKWARD (tile[i][j] = p_ij) ----------------
    const int bb = blockIdx.x - BB;
    const int b_hi = b_lo + b_cnt;                 // log_beta[b_hi] is the seed
    const h8* __restrict__ GB = (const h8*)E + (size_t)bb * 512 + tid * 2;
    float breg, rWp = 1.f, mp = 1.f;
    if (b_hi == TT - 1){
      breg = 0.f;
      if (w4 == 0) log_beta[(TT - 1) * (BB * SS) + bb * SS + lane] = 0.f;
    } else {
      breg = bwd_b[bb * SS + lane];
    }
    const float* __restrict__ sb = slx + bb * SS + lane;
    const float* __restrict__ mb = mask + bb;
    float* __restrict__ lb = log_beta + bb * SS + lane;
    float slc = sb[b_hi * (BB * SS)];
    float sl1 = sb[((b_hi - 1 >= 1) ? (b_hi - 1) : 1) * (BB * SS)];
    float sl2 = sb[((b_hi - 2 >= 1) ? (b_hi - 2) : 1) * (BB * SS)];
    float mc = mb[b_hi * BB];
    float m1 = mb[((b_hi - 1 >= 1) ? (b_hi - 1) : 1) * BB];
    float m2 = mb[((b_hi - 2 >= 1) ? (b_hi - 2) : 1) * BB];
    h8 Aa, Ab, Ba, Bb, Ca, Cb;
#define BLDG(NA, NB, rr) { int _tl = (rr); if (_tl < 0) _tl = 0; \
      const h8* _g = GB + (size_t)_tl * (BB * 512); NA = _g[0]; NB = _g[1]; }
    { // prologue: tile (b_cnt-1) -> slot 0; preload ring
      const h8* _g = GB + (size_t)(b_cnt - 1) * (BB * 512);
      h8 t0 = _g[0], t1 = _g[1];
      *(h8*)&tile[0][wrow * LSTR + wcol] = t0;
      *(h8*)&tile[0][wrow * LSTR + wcol + 8] = t1;
      BLDG(Aa, Ab, b_cnt - 2) BLDG(Ba, Bb, b_cnt - 3) BLDG(Ca, Cb, b_cnt - 4)
    }
    BARRIER();
#define BW_STEP(s, SL, NA, NB) { \
      if ((s) > 0) { \
        const int _ps = (SL + 2) % 3; \
        float dot = (fp[_ps][0][lane] + fp[_ps][1][lane]) \
                  + (fp[_ps][2][lane] + fp[_ps][3][lane]); \
        float v = __logf(fmaf(dot, rWp, EPSF)); \
        breg = (mp == 1.0f) ? v : 0.0f; \
        if (w4 == 0) lb[(b_hi - (s)) * (BB * SS)] = breg; \
      } \
      float wgt = __expf(slc + breg); \
      rWp = __builtin_amdgcn_rcpf(wave_sum_dpp(wgt)); \
      mp = mc; \
      slc = sl1; sl1 = sl2; mc = m1; m1 = m2; \
      { int _tn = b_hi - (s) - 3; if (_tn < 1) _tn = 1; \
        sl2 = sb[_tn * (BB * SS)]; m2 = mb[_tn * BB]; } \
      if ((s) + 1 < b_cnt) { \
        *(h8*)&tile[(SL + 1) % 3][wrow * LSTR + wcol] = NA; \
        *(h8*)&tile[(SL + 1) % 3][wrow * LSTR + wcol + 8] = NB; \
      } \
      BLDG(NA, NB, b_cnt - 5 - (s)) \
      { const f16* _tp = &tile[SL][lane * LSTR + w16]; \
        h8 _t0 = *(const h8*)_tp; h8 _t1 = *(const h8*)(_tp + 8); \
        float p0 = 0.f, p1 = 0.f, p2 = 0.f, p3 = 0.f; \
        mv8(p0, p1, p2, p3, wgt, _t0, w16); \
        mv8(p0, p1, p2, p3, wgt, _t1, w16 + 8); \
        fp[SL][w4][lane] = (p0 + p1) + (p2 + p3); } \
      BARRIER(); }
    int s = 0;
    for (;;){
      BW_STEP(s, 0, Aa, Ab) if (++s >= b_cnt) break;
      BW_STEP(s, 1, Ba, Bb) if (++s >= b_cnt) break;
      BW_STEP(s, 2, Ca, Cb) if (++s >= b_cnt) break;
    }
#undef BW_STEP
#undef BLDG
    { // epilogue: combine -> breg at t = b_lo
      const int ls = (b_cnt - 1) % 3;
      float dot = (fp[ls][0][lane] + fp[ls][1][lane])
                + (fp[ls][2][lane] + fp[ls][3][lane]);
      float v = __logf(fmaf(dot, rWp, EPSF));
      breg = (mp == 1.0f) ? v : 0.0f;
      if (w4 == 0){
        lb[b_lo * (BB * SS)] = breg;
        bwd_b[bb * SS + lane] = breg;
      }
    }
  }
}

// ================== R5 fallback scan (proven 402 us, 12.6 MB ws) ==================
__global__ __launch_bounds__(768) void scan_kernel(
    const float* __restrict__ slx, const float* __restrict__ mask,
    const float* __restrict__ il, const float* __restrict__ a,
    const float* __restrict__ w_base, const float* __restrict__ w_act,
    float* __restrict__ alpha, float* __restrict__ log_beta){
  const int lane = threadIdx.x & 63;
  const int w    = threadIdx.x >> 6;
  const bool is_fwd = (blockIdx.x < BB);
  const int b = is_fwd ? blockIdx.x : (blockIdx.x - BB);
  __shared__ __align__(16) float tile[3][SS * TS];
  __shared__ float rsp[3][8][SS];
  __shared__ float fpart[2][4][SS];
  __shared__ __align__(16) float aLDS[TT * AA];
  __shared__ float mLDS[TT];
  for (int idx = threadIdx.x; idx < TT * AA; idx += 768){
    int t = idx >> 3, k = idx & 7;
    aLDS[idx] = a[(t * BB + b) * AA + k];
  }
  for (int idx = threadIdx.x; idx < TT; idx += 768)
    mLDS[idx] = mask[idx * BB + b];
  if (w >= 4){
    const int pw = w - 4;
    const int jb = pw * 8;
    float wb[8], wa[8][8];
    #pragma unroll
    for (int jj = 0; jj < 8; ++jj){
      wb[jj] = w_base[lane * SS + jb + jj];
      #pragma unroll
      for (int k = 0; k < 8; ++k)
        wa[k][jj] = w_act[(k * SS + lane) * SS + jb + jj];
    }
    float aa[8], aan[8];
    {
      const int t0 = is_fwd ? 0 : (TT - 2);
      const float* __restrict__ ap = a + (t0 * BB + b) * AA;
      #pragma unroll
      for (int k = 0; k < 8; ++k) aa[k] = ap[k];
      const int t1 = is_fwd ? 1 : (TT - 3);
      const float* __restrict__ ap1 = a + (t1 * BB + b) * AA;
      #pragma unroll
      for (int k = 0; k < 8; ++k) aan[k] = ap1[k];
    }
    {
      float ev[8]; float racc = 0.f;
      #pragma unroll
      for (int jj = 0; jj < 8; ++jj){
        float u = wb[jj];
        #pragma unroll
        for (int k = 0; k < 8; ++k) u = fmaf(aa[k], wa[k][jj], u);
        ev[jj] = __expf(u); racc += ev[jj];
      }
      *(float4*)&tile[0][lane * TS + jb]     = make_float4(ev[0],ev[1],ev[2],ev[3]);
      *(float4*)&tile[0][lane * TS + jb + 4] = make_float4(ev[4],ev[5],ev[6],ev[7]);
      rsp[0][pw][lane] = racc;
    }
    BARRIER();
    int tw = 1;
    for (int s = 0; s < TT - 1; ++s){
      if (s <= TT - 3){
        #pragma unroll
        for (int k = 0; k < 8; ++k) aa[k] = aan[k];
        if (s + 1 <= TT - 3){
          const int tn = is_fwd ? (s + 2) : (TT - 4 - s);
          #pragma unroll
          for (int k = 0; k < 8; ++k) aan[k] = aLDS[tn * AA + k];
        }
        float ev[8]; float racc = 0.f;
        #pragma unroll
        for (int jj = 0; jj < 8; ++jj){
          float u = wb[jj];
          #pragma unroll
          for (int k = 0; k < 8; ++k) u = fmaf(aa[k], wa[k][jj], u);
          ev[jj] = __expf(u); racc += ev[jj];
        }
        *(float4*)&tile[tw][lane * TS + jb]     = make_float4(ev[0],ev[1],ev[2],ev[3]);
        *(float4*)&tile[tw][lane * TS + jb + 4] = make_float4(ev[4],ev[5],ev[6],ev[7]);
        rsp[tw][pw][lane] = racc;
        tw = (tw == 2) ? 0 : tw + 1;
      }
      BARRIER();
    }
  } else if (is_fwd){
    const int wb16 = __builtin_amdgcn_readfirstlane(w * 16);
    float u = __expf(slx[b * SS + lane] + il[lane]);
    float c = __builtin_amdgcn_rcpf(wave_sum_dpp(u));
    if (w == 0) alpha[b * SS + lane] = u * c;
    float slxn = slx[(BB + b) * SS + lane];
    float elxc = 0.f;
    BARRIER();
    int ts = 0;
    for (int s = 0; s < TT - 1; ++s){
      if (s > 0){
        const int fs = (s - 1) & 1;
        float S = (fpart[fs][0][lane] + fpart[fs][1][lane])
                + (fpart[fs][2][lane] + fpart[fs][3][lane]);
        u = elxc * fmaf(c, S, SEPS);
        c = __builtin_amdgcn_rcpf(wave_sum_dpp(u));
        if (w == 0) alpha[(s * BB + b) * SS + lane] = u * c;
      }
      float rs = ((rsp[ts][0][lane] + rsp[ts][1][lane]) + (rsp[ts][2][lane] + rsp[ts][3][lane]))
               + ((rsp[ts][4][lane] + rsp[ts][5][lane]) + (rsp[ts][6][lane] + rsp[ts][7][lane]));
      float va = u * __builtin_amdgcn_rcpf(rs);
      const float* __restrict__ tp = &tile[ts][0];
      float a0 = 0.f, a1 = 0.f, a2 = 0.f, a3 = 0.f;
      #pragma unroll
      for (int r = 0; r < 16; r += 4){
        a0 = fmaf(readlane_f(va, wb16 + r    ), tp[(wb16 + r    ) * TS + lane], a0);
        a1 = fmaf(readlane_f(va, wb16 + r + 1), tp[(wb16 + r + 1) * TS + lane], a1);
        a2 = fmaf(readlane_f(va, wb16 + r + 2), tp[(wb16 + r + 2) * TS + lane], a2);
        a3 = fmaf(readlane_f(va, wb16 + r + 3), tp[(wb16 + r + 3) * TS + lane], a3);
      }
      fpart[s & 1][w][lane] = (a0 + a1) + (a2 + a3);
      elxc = __expf(slxn);
      if (s + 2 <= TT - 1) slxn = slx[((s + 2) * BB + b) * SS + lane];
      ts = (ts == 2) ? 0 : ts + 1;
      BARRIER();
    }
    {
      const int fs = (TT - 2) & 1;
      float S = (fpart[fs][0][lane] + fpart[fs][1][lane])
              + (fpart[fs][2][lane] + fpart[fs][3][lane]);
      u = elxc * fmaf(c, S, SEPS);
      c = __builtin_amdgcn_rcpf(wave_sum_dpp(u));
      if (w == 0) alpha[((TT - 1) * BB + b) * SS + lane] = u * c;
    }
  } else {
    const int wb16 = __builtin_amdgcn_readfirstlane(w * 16);
    float breg = 0.f, rWc = 1.f;
    if (w == 0) log_beta[((TT - 1) * BB + b) * SS + lane] = 0.f;
    float slxc = slx[((TT - 1) * BB + b) * SS + lane];
    float mprev = 1.f;
    BARRIER();
    int ts = 0, pts = 2;
    for (int s = 0; s < TT - 1; ++s){
      if (s > 0){
        const int fs = (s - 1) & 1;
        float eh = (fpart[fs][0][lane] + fpart[fs][1][lane])
                 + (fpart[fs][2][lane] + fpart[fs][3][lane]);
        float rsv = ((rsp[pts][0][lane] + rsp[pts][1][lane]) + (rsp[pts][2][lane] + rsp[pts][3][lane]))
                  + ((rsp[pts][4][lane] + rsp[pts][5][lane]) + (rsp[pts][6][lane] + rsp[pts][7][lane]));
        float v = __logf(fmaf(eh * __builtin_amdgcn_rcpf(rsv), rWc, EPSF));
        breg = (mprev == 1.0f) ? v : 0.0f;
        if (w == 0) log_beta[((TT - 1 - s) * BB + b) * SS + lane] = breg;
      }
      float wgt = __expf(slxc + breg);
      float W = wave_sum_dpp(wgt);
      rWc = __builtin_amdgcn_rcpf(W);
      const float* __restrict__ tp = &tile[ts][lane * TS + wb16];
      float4 e0 = *(const float4*)(tp);
      float4 e1 = *(const float4*)(tp + 4);
      float4 e2 = *(const float4*)(tp + 8);
      float4 e3 = *(const float4*)(tp + 12);
      float a0 = 0.f, a1 = 0.f, a2 = 0.f, a3 = 0.f;
      a0 = fmaf(readlane_f(wgt, wb16 + 0),  e0.x, a0);
      a1 = fmaf(readlane_f(wgt, wb16 + 1),  e0.y, a1);
      a2 = fmaf(readlane_f(wgt, wb16 + 2),  e0.z, a2);
      a3 = fmaf(readlane_f(wgt, wb16 + 3),  e0.w, a3);
      a0 = fmaf(readlane_f(wgt, wb16 + 4),  e1.x, a0);
      a1 = fmaf(readlane_f(wgt, wb16 + 5),  e1.y, a1);
      a2 = fmaf(readlane_f(wgt, wb16 + 6),  e1.z, a2);
      a3 = fmaf(readlane_f(wgt, wb16 + 7),  e1.w, a3);
      a0 = fmaf(readlane_f(wgt, wb16 + 8),  e2.x, a0);
      a1 = fmaf(readlane_f(wgt, wb16 + 9),  e2.y, a1);
      a2 = fmaf(readlane_f(wgt, wb16 + 10), e2.z, a2);
      a3 = fmaf(readlane_f(wgt, wb16 + 11), e2.w, a3);
      a0 = fmaf(readlane_f(wgt, wb16 + 12), e3.x, a0);
      a1 = fmaf(readlane_f(wgt, wb16 + 13), e3.y, a1);
      a2 = fmaf(readlane_f(wgt, wb16 + 14), e3.z, a2);
      a3 = fmaf(readlane_f(wgt, wb16 + 15), e3.w, a3);
      fpart[s & 1][w][lane] = (a0 + a1) + (a2 + a3);
      mprev = mLDS[TT - 1 - s];
      if (s <= TT - 3) slxc = slx[((TT - 2 - s) * BB + b) * SS + lane];
      pts = ts; ts = (ts == 2) ? 0 : ts + 1;
      BARRIER();
    }
    {
      const int fs = (TT - 2) & 1;
      float eh = (fpart[fs][0][lane] + fpart[fs][1][lane])
               + (fpart[fs][2][lane] + fpart[fs][3][lane]);
      float rsv = ((rsp[pts][0][lane] + rsp[pts][1][lane]) + (rsp[pts][2][lane] + rsp[pts][3][lane]))
                + ((rsp[pts][4][lane] + rsp[pts][5][lane]) + (rsp[pts][6][lane] + rsp[pts][7][lane]));
      float v = __logf(fmaf(eh * __builtin_amdgcn_rcpf(rsv), rWc, EPSF));
      breg = (mprev == 1.0f) ? v : 0.0f;
      if (w == 0) log_beta[b * SS + lane] = breg;
    }
  }
}

// --- q_z = softmax(log(alpha+EPS) + log_beta)
__global__ __launch_bounds__(256) void qz_kernel(
    const float* __restrict__ alpha, const float* __restrict__ log_beta,
    float* __restrict__ out){
  const int lane = threadIdx.x & 63;
  const int w = threadIdx.x >> 6;
  const int row = blockIdx.x * 4 + w;
  float v = __logf(alpha[row * SS + lane] + EPSF) + log_beta[row * SS + lane];
  float mx = wave_max(v);
  float e = __expf(v - mx);
  float sm = wave_sum(e);
  out[row * SS + lane] = e * __builtin_amdgcn_rcpf(sm);
}

extern "C" void kernel_launch(void* const* d_in, const int* in_sizes, int n_in,
                              void* d_out, int out_size, void* d_ws, size_t ws_size,
                              hipStream_t stream){
  const float* x      = (const float*)d_in[0];
  const float* a      = (const float*)d_in[1];
  const float* mask   = (const float*)d_in[2];
  const float* mu     = (const float*)d_in[3];
  const float* logv   = (const float*)d_in[4];
  const float* il     = (const float*)d_in[5];
  const float* w_base = (const float*)d_in[6];
  const float* w_act  = (const float*)d_in[7];
  float* out = (float*)d_out;

  float* ws = (float*)d_ws;
  const size_t TBS = (size_t)TT * BB * SS;
  float* iv       = ws;                   // 2048 (+cs, pad to 4096)
  float* cs       = ws + 2048;
  float* slx      = ws + 4096;
  float* alpha    = slx + TBS;
  float* log_beta = alpha + TBS;
  float* fwd_u    = log_beta + TBS;       // 2048
  float* bwd_b    = fwd_u + 2048;         // 2048 (pad to 8192)
  const size_t base = 4096 + 3 * TBS + 8192;   // floats
  f16* ET = (f16*)(ws + base);

  int W = 0;
  const int tiers[4] = {256, 128, 64, 32};
  for (int i = 0; i < 4; ++i){
    const size_t need = base * 4 + 2 * (size_t)tiers[i] * BB * 4096 * 2;
    if (need <= ws_size){ W = tiers[i]; break; }
  }

  prep_kernel<<<8, 256, 0, stream>>>(logv, iv, cs);
  logpx_kernel<<<TT * BB / 4, 256, 0, stream>>>(x, mu, iv, cs, slx);
  if (W > 0){
    f16* E = ET + (size_t)W * BB * 4096;
    const int nw = (TT - 1 + W - 1) / W;
    for (int k = 0; k < nw; ++k){
      const int f_lo = k * W;
      const int f_cnt = ((TT - 1) - f_lo < W) ? ((TT - 1) - f_lo) : W;
      const int b_hi = (TT - 1) - k * W;
      const int b_lo = (b_hi - W > 0) ? (b_hi - W) : 0;
      const int b_cnt = b_hi - b_lo;
      produce_kernel<<<(f_cnt + b_cnt) * 2, 256, 0, stream>>>(
          a, w_base, w_act, ET, E, f_lo, f_cnt, b_lo, b_cnt);
      scan_win_kernel<<<2 * BB, 256, 0, stream>>>(
          slx, mask, il, ET, E, alpha, log_beta, fwd_u, bwd_b,
          f_lo, f_cnt, b_lo, b_cnt);
    }
  } else {
    scan_kernel<<<2 * BB, 768, 0, stream>>>(slx, mask, il, a, w_base, w_act,
                                            alpha, log_beta);
  }
  qz_kernel<<<TT * BB / 4, 256, 0, stream>>>(alpha, log_beta, out);
}